// Round 2
// baseline (813.799 us; speedup 1.0000x reference)
//
#include <hip/hip_runtime.h>
#include <cstdint>
#include <cstddef>

typedef unsigned long long ull;

#define KTOP   1000
#define CAP    4096      // candidate gather capacity per (b,c)
#define HBITS  14
#define HB     (1 << HBITS)          // 16384 histogram bins (top-14 float bits)
#define HSHIFT (32 - HBITS)
#define ROWS   1024      // padded rank capacity (>= KTOP)
#define WORDS  16        // 1024 / 64 bitmask words per row

// ---------------- Kernel 1: softmax + SSD decode + fused score histogram ----------------
__global__ void decode_kernel(const float* __restrict__ loc,
                              const float* __restrict__ conf,
                              const float* __restrict__ prior,
                              const float* __restrict__ cthp,
                              float* __restrict__ scores,   // [B*Cfg][P]
                              float* __restrict__ cs,       // [B][P][4] center-size
                              unsigned* __restrict__ hist,  // [B*Cfg][HB]
                              int B, int C, int P) {
#pragma clang fp contract(off)
    int t = blockIdx.x * blockDim.x + threadIdx.x;
    if (t >= B * P) return;
    int b = t / P;
    int p = t - b * P;
    float cth = *cthp;

    // softmax over class dim (C small)
    float x[8];
    float m = -INFINITY;
    for (int c = 0; c < C; ++c) {
        x[c] = conf[((size_t)b * C + c) * P + p];
        m = fmaxf(m, x[c]);
    }
    float sum = 0.f;
    for (int c = 0; c < C; ++c) {
        x[c] = expf(x[c] - m);
        sum += x[c];
    }
    for (int c = 1; c < C; ++c) {
        float v = x[c] / sum;
        int bc = b * (C - 1) + (c - 1);
        scores[(size_t)bc * P + p] = v;
        if (v >= cth) {
            unsigned key = __float_as_uint(v);
            atomicAdd(&hist[(size_t)bc * HB + (key >> HSHIFT)], 1u);
        }
    }

    // decode
    float l0 = loc[((size_t)b * 4 + 0) * P + p];
    float l1 = loc[((size_t)b * 4 + 1) * P + p];
    float l2 = loc[((size_t)b * 4 + 2) * P + p];
    float l3 = loc[((size_t)b * 4 + 3) * P + p];
    float pcx = prior[(size_t)p * 4 + 0];
    float pcy = prior[(size_t)p * 4 + 1];
    float pw  = prior[(size_t)p * 4 + 2];
    float ph  = prior[(size_t)p * 4 + 3];

    float cx = pcx + (l0 * 0.1f) * pw;
    float cy = pcy + (l1 * 0.1f) * ph;
    float w  = pw * expf(l2 * 0.2f);
    float h  = ph * expf(l3 * 0.2f);

    size_t o = ((size_t)b * P + p) * 4;
    cs[o + 0] = cx;
    cs[o + 1] = cy;
    cs[o + 2] = w;
    cs[o + 3] = h;
}

// ---------------- Kernel 2: per-(b,c) pivot bin from histogram ----------------
__global__ void __launch_bounds__(1024)
pivot_kernel(const unsigned* __restrict__ hist, unsigned* __restrict__ pivot) {
    int bc  = blockIdx.x;
    int tid = threadIdx.x;
    const unsigned* h = hist + (size_t)bc * HB;
    __shared__ unsigned psum[1024];
    __shared__ int s_t;
    __shared__ unsigned s_before;

    const int per = HB / 1024;           // 16 bins per thread
    int base = tid * per;
    unsigned sum = 0;
    for (int i = 0; i < per; ++i) sum += h[base + i];
    psum[tid] = sum;
    __syncthreads();

    if (tid == 0) {
        unsigned cum = 0;
        int st = -1;
        for (int t = 1023; t >= 0; --t) {
            if (cum + psum[t] >= (unsigned)KTOP) { st = t; s_before = cum; break; }
            cum += psum[t];
        }
        s_t = st;
        if (st < 0) pivot[bc] = 0u;      // fewer than KTOP valid: take all
    }
    __syncthreads();
    if (s_t >= 0 && tid == s_t) {
        unsigned cum = s_before;
        for (int i = per - 1; i >= 0; --i) {
            cum += h[base + i];
            if (cum >= (unsigned)KTOP) { pivot[bc] = (unsigned)(base + i); break; }
        }
    }
}

// ---------------- Kernel 3: GPU-wide gather of candidates >= pivot ----------------
__global__ void gather_kernel(const float* __restrict__ scores,
                              const unsigned* __restrict__ pivot,
                              unsigned* __restrict__ cnt,
                              ull* __restrict__ cand,
                              const float* __restrict__ cthp, int P) {
    int bc = blockIdx.x;
    const float* s = scores + (size_t)bc * P;
    float cth = *cthp;
    unsigned pv = pivot[bc];
    int nchunk = gridDim.y;
    int chunk = (P + nchunk - 1) / nchunk;
    int lo = blockIdx.y * chunk;
    int hi = lo + chunk; if (hi > P) hi = P;
    for (int p = lo + threadIdx.x; p < hi; p += blockDim.x) {
        float v = s[p];
        if (v >= cth) {
            unsigned k = __float_as_uint(v);
            if ((k >> HSHIFT) >= pv) {
                unsigned pos = atomicAdd(&cnt[bc], 1u);
                if (pos < CAP)
                    cand[(size_t)bc * CAP + pos] = ((ull)k << 32) | (unsigned)(~(unsigned)p);
            }
        }
    }
}

// ---------------- Kernel 4: per-(b,c) bitonic sort + export sorted boxes ----------------
__global__ void __launch_bounds__(1024)
sort_kernel(const ull* __restrict__ cand,
            const unsigned* __restrict__ cnt,
            const float* __restrict__ cs,
            float* __restrict__ rows,      // [NBC][KTOP][5] score,cx,cy,w,h
            float* __restrict__ bx1, float* __restrict__ by1,
            float* __restrict__ bx2, float* __restrict__ by2,
            float* __restrict__ bar,       // SoA [NBC][ROWS]
            int* __restrict__ nselArr,
            int P, int Cfg) {
#pragma clang fp contract(off)
    int bc  = blockIdx.x;
    int b   = bc / Cfg;
    int tid = threadIdx.x;
    __shared__ ull sbuf[CAP];

    int M = (int)cnt[bc]; if (M > CAP) M = CAP;
    int nsel = M < KTOP ? M : KTOP;
    if (tid == 0) nselArr[bc] = nsel;

    int n = 1024;
    while (n < M) n <<= 1;
    for (int i = tid; i < n; i += 1024)
        sbuf[i] = (i < M) ? cand[(size_t)bc * CAP + i] : 0ull;
    __syncthreads();

    for (unsigned k = 2; k <= (unsigned)n; k <<= 1) {
        for (unsigned j = k >> 1; j > 0; j >>= 1) {
            for (unsigned i = tid; i < (unsigned)n; i += 1024) {
                unsigned ixj = i ^ j;
                if (ixj > i) {
                    bool up = ((i & k) == 0u);
                    ull a = sbuf[i], bb = sbuf[ixj];
                    if ((a > bb) == up) { sbuf[i] = bb; sbuf[ixj] = a; }
                }
            }
            __syncthreads();
        }
    }

    for (int r = tid; r < nsel; r += 1024) {
        ull e = sbuf[n - 1 - r];
        float sc = __uint_as_float((unsigned)(e >> 32));
        int idx = (int)(~(unsigned)e);
        const float* c4 = cs + ((size_t)b * P + idx) * 4;
        float cx = c4[0], cy = c4[1], w = c4[2], h = c4[3];
        float x1 = cx - w / 2.f, y1 = cy - h / 2.f;
        float x2 = cx + w / 2.f, y2 = cy + h / 2.f;
        size_t sb = (size_t)bc * ROWS + r;
        bx1[sb] = x1; by1[sb] = y1; bx2[sb] = x2; by2[sb] = y2;
        bar[sb] = fmaxf(x2 - x1, 0.f) * fmaxf(y2 - y1, 0.f);
        float* rr = rows + ((size_t)bc * KTOP + r) * 5;
        rr[0] = sc; rr[1] = cx; rr[2] = cy; rr[3] = w; rr[4] = h;
    }
}

// ---------------- Kernel 5: GPU-wide suppression bitmask matrix ----------------
__global__ void __launch_bounds__(1024)
mask_kernel(const float* __restrict__ bx1, const float* __restrict__ by1,
            const float* __restrict__ bx2, const float* __restrict__ by2,
            const float* __restrict__ bar,
            const int* __restrict__ nselArr,
            const float* __restrict__ nthp,
            ull* __restrict__ mask) {       // [NBC][ROWS][WORDS]
#pragma clang fp contract(off)
    int bc   = blockIdx.x;
    int tile = blockIdx.y;                  // 16 tiles x 64 rows
    int tid  = threadIdx.x;
    int nsel = nselArr[bc];
    float nth = *nthp;

    __shared__ float sx1[ROWS], sy1[ROWS], sx2[ROWS], sy2[ROWS], sar[ROWS];
    size_t sb = (size_t)bc * ROWS;
    if (tid < nsel) {
        sx1[tid] = bx1[sb + tid]; sy1[tid] = by1[sb + tid];
        sx2[tid] = bx2[sb + tid]; sy2[tid] = by2[sb + tid];
        sar[tid] = bar[sb + tid];
    }
    __syncthreads();

    int i = tile * 64 + (tid >> 4);
    int w = tid & 15;
    if (i >= nsel) return;

    float xi1 = sx1[i], yi1 = sy1[i], xi2 = sx2[i], yi2 = sy2[i], ai = sar[i];
    ull bits = 0ull;
    int j0 = w << 6;
    // rotate start by w*4 to break the 16-way LDS bank aliasing across word-groups
    for (int jj0 = 0; jj0 < 64; ++jj0) {
        int jj = (jj0 + (w << 2)) & 63;
        int j = j0 + jj;
        if (j > i && j < nsel) {
            float ww = fmaxf(fminf(xi2, sx2[j]) - fmaxf(xi1, sx1[j]), 0.f);
            float hh = fmaxf(fminf(yi2, sy2[j]) - fmaxf(yi1, sy1[j]), 0.f);
            float inter = ww * hh;
            float uni = ai + sar[j] - inter;
            float iou = inter / fmaxf(uni, 1e-12f);
            if (iou > nth) bits |= 1ull << jj;
        }
    }
    mask[(((size_t)bc * ROWS + i) << 4) + w] = bits;
}

// ---------------- Kernel 6: serial bit-OR reduction + compact + write ----------------
__global__ void __launch_bounds__(64)
reduce_pack_kernel(const ull* __restrict__ mask,
                   const int* __restrict__ nselArr,
                   const float* __restrict__ rows,
                   float* __restrict__ out) {
    int bc   = blockIdx.x;
    int lane = threadIdx.x;
    int nsel = nselArr[bc];
    const ull* mrow = mask + ((size_t)bc * ROWS << 4);

    ull S = 0ull;                            // suppressed bitmap, word `lane` (lanes 0..15)
    for (int i = 0; i < nsel; ++i) {
        ull r = (lane < WORDS) ? mrow[((size_t)i << 4) + lane] : 0ull;  // independent of S -> pipelines
        ull Sw = __shfl(S, i >> 6);
        bool kept = ((Sw >> (i & 63)) & 1ull) == 0ull;
        if (kept) S |= r;
    }

    int base_i = lane << 6;
    ull valid = 0ull;
    if (lane < WORDS) {
        int rem = nsel - base_i;
        if (rem > 0) valid = (rem >= 64) ? ~0ull : ((1ull << rem) - 1ull);
    }
    ull K = (~S) & valid;
    int c = __popcll(K);
    int x = c;
    for (int d = 1; d < 64; d <<= 1) {
        int y = __shfl_up(x, d);
        if (lane >= d) x += y;
    }
    int pos = x - c;                          // exclusive prefix of kept counts

    const float* rbase = rows + (size_t)bc * KTOP * 5;
    float* obase = out + (size_t)bc * KTOP * 5;
    for (int bit = 0; bit < 64; ++bit) {
        if ((K >> bit) & 1ull) {
            int i = base_i + bit;
            const float* rr = rbase + i * 5;
            float* oo = obase + pos * 5;
            oo[0] = rr[0]; oo[1] = rr[1]; oo[2] = rr[2]; oo[3] = rr[3]; oo[4] = rr[4];
            ++pos;
        }
    }
}

// ------------------------------- launcher -------------------------------
extern "C" void kernel_launch(void* const* d_in, const int* in_sizes, int n_in,
                              void* d_out, int out_size, void* d_ws, size_t ws_size,
                              hipStream_t stream) {
    (void)n_in; (void)ws_size;
    const float* loc   = (const float*)d_in[0];
    const float* conf  = (const float*)d_in[1];
    const float* prior = (const float*)d_in[2];
    const float* cth   = (const float*)d_in[3];
    const float* nth   = (const float*)d_in[4];
    float* out = (float*)d_out;

    int P   = in_sizes[2] / 4;
    int B   = in_sizes[0] / (4 * P);
    int C   = in_sizes[1] / (B * P);
    int Cfg = C - 1;
    int NBC = B * Cfg;

    // ---- carve workspace (256B aligned sections; 8B types first) ----
    char* base = (char*)d_ws;
    size_t off = 0;
    auto carve = [&](size_t bytes) { char* p = base + off; off = (off + bytes + 255) & ~(size_t)255; return p; };

    ull*      cand   = (ull*)     carve((size_t)NBC * CAP * 8);
    ull*      mask   = (ull*)     carve((size_t)NBC * ROWS * WORDS * 8);
    float*    scores = (float*)   carve((size_t)NBC * P * 4);
    float*    cs     = (float*)   carve((size_t)B * P * 4 * 4);
    float*    rows   = (float*)   carve((size_t)NBC * KTOP * 5 * 4);
    float*    bx1    = (float*)   carve((size_t)NBC * ROWS * 4);
    float*    by1    = (float*)   carve((size_t)NBC * ROWS * 4);
    float*    bx2    = (float*)   carve((size_t)NBC * ROWS * 4);
    float*    by2    = (float*)   carve((size_t)NBC * ROWS * 4);
    float*    bar    = (float*)   carve((size_t)NBC * ROWS * 4);
    unsigned* hist   = (unsigned*)carve((size_t)NBC * HB * 4 + (size_t)NBC * 4);  // hist + cnt contiguous
    unsigned* cnt    = hist + (size_t)NBC * HB;
    unsigned* pivot  = (unsigned*)carve((size_t)NBC * 4);
    int*      nselA  = (int*)     carve((size_t)NBC * 4);

    hipMemsetAsync(hist, 0, (size_t)NBC * HB * 4 + (size_t)NBC * 4, stream);
    hipMemsetAsync(out, 0, (size_t)out_size * 4, stream);

    int n1 = B * P;
    decode_kernel<<<(n1 + 255) / 256, 256, 0, stream>>>(loc, conf, prior, cth, scores, cs, hist, B, C, P);
    pivot_kernel<<<NBC, 1024, 0, stream>>>(hist, pivot);
    gather_kernel<<<dim3(NBC, 32), 256, 0, stream>>>(scores, pivot, cnt, cand, cth, P);
    sort_kernel<<<NBC, 1024, 0, stream>>>(cand, cnt, cs, rows, bx1, by1, bx2, by2, bar, nselA, P, Cfg);
    mask_kernel<<<dim3(NBC, ROWS / 64), 1024, 0, stream>>>(bx1, by1, bx2, by2, bar, nselA, nth, mask);
    reduce_pack_kernel<<<NBC, 64, 0, stream>>>(mask, nselA, rows, out);
}

// Round 3
// 639.165 us; speedup vs baseline: 1.2732x; 1.2732x over previous
//
#include <hip/hip_runtime.h>
#include <cstdint>
#include <cstddef>

typedef unsigned long long ull;

#define KTOP   1000
#define CAP    4096      // candidate gather capacity per (b,c)
#define HBITS  14
#define HB     (1 << HBITS)          // 16384 histogram bins (top-14 float bits)
#define HSHIFT (32 - HBITS)
#define ROWS   1024      // padded rank capacity (>= KTOP)
#define WORDS  16        // 1024 / 64 bitmask words per row

// ---------------- Kernel 1: softmax + SSD decode + fused score histogram ----------------
__global__ void decode_kernel(const float* __restrict__ loc,
                              const float* __restrict__ conf,
                              const float* __restrict__ prior,
                              const float* __restrict__ cthp,
                              float* __restrict__ scores,   // [B*Cfg][P]
                              float* __restrict__ cs,       // [B][P][4] center-size
                              unsigned* __restrict__ hist,  // [B*Cfg][HB]
                              int B, int C, int P) {
#pragma clang fp contract(off)
    int t = blockIdx.x * blockDim.x + threadIdx.x;
    if (t >= B * P) return;
    int b = t / P;
    int p = t - b * P;
    float cth = *cthp;

    // softmax over class dim (C small)
    float x[8];
    float m = -INFINITY;
    for (int c = 0; c < C; ++c) {
        x[c] = conf[((size_t)b * C + c) * P + p];
        m = fmaxf(m, x[c]);
    }
    float sum = 0.f;
    for (int c = 0; c < C; ++c) {
        x[c] = expf(x[c] - m);
        sum += x[c];
    }
    for (int c = 1; c < C; ++c) {
        float v = x[c] / sum;
        int bc = b * (C - 1) + (c - 1);
        scores[(size_t)bc * P + p] = v;
        if (v >= cth) {
            unsigned key = __float_as_uint(v);
            atomicAdd(&hist[(size_t)bc * HB + (key >> HSHIFT)], 1u);
        }
    }

    // decode
    float l0 = loc[((size_t)b * 4 + 0) * P + p];
    float l1 = loc[((size_t)b * 4 + 1) * P + p];
    float l2 = loc[((size_t)b * 4 + 2) * P + p];
    float l3 = loc[((size_t)b * 4 + 3) * P + p];
    float pcx = prior[(size_t)p * 4 + 0];
    float pcy = prior[(size_t)p * 4 + 1];
    float pw  = prior[(size_t)p * 4 + 2];
    float ph  = prior[(size_t)p * 4 + 3];

    float cx = pcx + (l0 * 0.1f) * pw;
    float cy = pcy + (l1 * 0.1f) * ph;
    float w  = pw * expf(l2 * 0.2f);
    float h  = ph * expf(l3 * 0.2f);

    size_t o = ((size_t)b * P + p) * 4;
    cs[o + 0] = cx;
    cs[o + 1] = cy;
    cs[o + 2] = w;
    cs[o + 3] = h;
}

// ---------------- Kernel 2: per-(b,c) pivot bin from histogram ----------------
__global__ void __launch_bounds__(1024)
pivot_kernel(const unsigned* __restrict__ hist, unsigned* __restrict__ pivot) {
    int bc  = blockIdx.x;
    int tid = threadIdx.x;
    const unsigned* h = hist + (size_t)bc * HB;
    __shared__ unsigned psum[1024];
    __shared__ int s_t;
    __shared__ unsigned s_before;

    const int per = HB / 1024;           // 16 bins per thread
    int base = tid * per;
    unsigned sum = 0;
    for (int i = 0; i < per; ++i) sum += h[base + i];
    psum[tid] = sum;
    __syncthreads();

    if (tid == 0) {
        unsigned cum = 0;
        int st = -1;
        for (int t = 1023; t >= 0; --t) {
            if (cum + psum[t] >= (unsigned)KTOP) { st = t; s_before = cum; break; }
            cum += psum[t];
        }
        s_t = st;
        if (st < 0) pivot[bc] = 0u;      // fewer than KTOP valid: take all
    }
    __syncthreads();
    if (s_t >= 0 && tid == s_t) {
        unsigned cum = s_before;
        for (int i = per - 1; i >= 0; --i) {
            cum += h[base + i];
            if (cum >= (unsigned)KTOP) { pivot[bc] = (unsigned)(base + i); break; }
        }
    }
}

// ---------------- Kernel 3: GPU-wide gather of candidates >= pivot ----------------
__global__ void gather_kernel(const float* __restrict__ scores,
                              const unsigned* __restrict__ pivot,
                              unsigned* __restrict__ cnt,
                              ull* __restrict__ cand,
                              const float* __restrict__ cthp, int P) {
    int bc = blockIdx.x;
    const float* s = scores + (size_t)bc * P;
    float cth = *cthp;
    unsigned pv = pivot[bc];
    int nchunk = gridDim.y;
    int chunk = (P + nchunk - 1) / nchunk;
    int lo = blockIdx.y * chunk;
    int hi = lo + chunk; if (hi > P) hi = P;
    for (int p = lo + threadIdx.x; p < hi; p += blockDim.x) {
        float v = s[p];
        if (v >= cth) {
            unsigned k = __float_as_uint(v);
            if ((k >> HSHIFT) >= pv) {
                unsigned pos = atomicAdd(&cnt[bc], 1u);
                if (pos < CAP)
                    cand[(size_t)bc * CAP + pos] = ((ull)k << 32) | (unsigned)(~(unsigned)p);
            }
        }
    }
}

// ---------------- Kernel 4: per-(b,c) bitonic sort + export sorted boxes ----------------
__global__ void __launch_bounds__(1024)
sort_kernel(const ull* __restrict__ cand,
            const unsigned* __restrict__ cnt,
            const float* __restrict__ cs,
            float* __restrict__ rows,      // [NBC][KTOP][5] score,cx,cy,w,h
            float* __restrict__ bx1, float* __restrict__ by1,
            float* __restrict__ bx2, float* __restrict__ by2,
            float* __restrict__ bar,       // SoA [NBC][ROWS]
            int* __restrict__ nselArr,
            int P, int Cfg) {
#pragma clang fp contract(off)
    int bc  = blockIdx.x;
    int b   = bc / Cfg;
    int tid = threadIdx.x;
    __shared__ ull sbuf[CAP];

    int M = (int)cnt[bc]; if (M > CAP) M = CAP;
    int nsel = M < KTOP ? M : KTOP;
    if (tid == 0) nselArr[bc] = nsel;

    int n = 1024;
    while (n < M) n <<= 1;
    for (int i = tid; i < n; i += 1024)
        sbuf[i] = (i < M) ? cand[(size_t)bc * CAP + i] : 0ull;
    __syncthreads();

    for (unsigned k = 2; k <= (unsigned)n; k <<= 1) {
        for (unsigned j = k >> 1; j > 0; j >>= 1) {
            for (unsigned i = tid; i < (unsigned)n; i += 1024) {
                unsigned ixj = i ^ j;
                if (ixj > i) {
                    bool up = ((i & k) == 0u);
                    ull a = sbuf[i], bb = sbuf[ixj];
                    if ((a > bb) == up) { sbuf[i] = bb; sbuf[ixj] = a; }
                }
            }
            __syncthreads();
        }
    }

    for (int r = tid; r < nsel; r += 1024) {
        ull e = sbuf[n - 1 - r];
        float sc = __uint_as_float((unsigned)(e >> 32));
        int idx = (int)(~(unsigned)e);
        const float* c4 = cs + ((size_t)b * P + idx) * 4;
        float cx = c4[0], cy = c4[1], w = c4[2], h = c4[3];
        float x1 = cx - w / 2.f, y1 = cy - h / 2.f;
        float x2 = cx + w / 2.f, y2 = cy + h / 2.f;
        size_t sb = (size_t)bc * ROWS + r;
        bx1[sb] = x1; by1[sb] = y1; bx2[sb] = x2; by2[sb] = y2;
        bar[sb] = fmaxf(x2 - x1, 0.f) * fmaxf(y2 - y1, 0.f);
        float* rr = rows + ((size_t)bc * KTOP + r) * 5;
        rr[0] = sc; rr[1] = cx; rr[2] = cy; rr[3] = w; rr[4] = h;
    }
}

// ---------------- Kernel 5: GPU-wide suppression bitmask matrix ----------------
__global__ void __launch_bounds__(1024)
mask_kernel(const float* __restrict__ bx1, const float* __restrict__ by1,
            const float* __restrict__ bx2, const float* __restrict__ by2,
            const float* __restrict__ bar,
            const int* __restrict__ nselArr,
            const float* __restrict__ nthp,
            ull* __restrict__ mask) {       // [NBC][ROWS][WORDS]
#pragma clang fp contract(off)
    int bc   = blockIdx.x;
    int tile = blockIdx.y;                  // 16 tiles x 64 rows
    int tid  = threadIdx.x;
    int nsel = nselArr[bc];
    float nth = *nthp;

    __shared__ float sx1[ROWS], sy1[ROWS], sx2[ROWS], sy2[ROWS], sar[ROWS];
    size_t sb = (size_t)bc * ROWS;
    if (tid < nsel) {
        sx1[tid] = bx1[sb + tid]; sy1[tid] = by1[sb + tid];
        sx2[tid] = bx2[sb + tid]; sy2[tid] = by2[sb + tid];
        sar[tid] = bar[sb + tid];
    }
    __syncthreads();

    int i = tile * 64 + (tid >> 4);
    int w = tid & 15;
    if (i >= nsel) return;

    float xi1 = sx1[i], yi1 = sy1[i], xi2 = sx2[i], yi2 = sy2[i], ai = sar[i];
    ull bits = 0ull;
    int j0 = w << 6;
    // rotate start by w*4 to break the 16-way LDS bank aliasing across word-groups
    for (int jj0 = 0; jj0 < 64; ++jj0) {
        int jj = (jj0 + (w << 2)) & 63;
        int j = j0 + jj;
        if (j > i && j < nsel) {
            float ww = fmaxf(fminf(xi2, sx2[j]) - fmaxf(xi1, sx1[j]), 0.f);
            float hh = fmaxf(fminf(yi2, sy2[j]) - fmaxf(yi1, sy1[j]), 0.f);
            float inter = ww * hh;
            float uni = ai + sar[j] - inter;
            float iou = inter / fmaxf(uni, 1e-12f);
            if (iou > nth) bits |= 1ull << jj;
        }
    }
    mask[(((size_t)bc * ROWS + i) << 4) + w] = bits;
}

// ---------------- Kernel 6: chunked serial bit-OR reduction + compact + write ----------------
// One wave per (b,c). Double-buffered LDS staging of 64-row chunks (8 KB each);
// next chunk is loaded into registers BEFORE processing the current chunk and
// written to LDS after, so global latency overlaps the serial recurrence.
// The serial chain per rank is 3 VALU ops on `cur` (the current 64-bit word of
// the suppressed bitmap); the diagonal mask word is an LDS broadcast read
// hoisted off-chain by unrolling.
__global__ void __launch_bounds__(64)
reduce_pack_kernel(const ull* __restrict__ mask,
                   const int* __restrict__ nselArr,
                   const float* __restrict__ rows,
                   float* __restrict__ out) {
    int bc   = blockIdx.x;
    int lane = threadIdx.x;                 // 64 threads = 1 wave
    int nsel = nselArr[bc];
    const ull* mrow = mask + ((size_t)bc * ROWS << 4);

    __shared__ ull sm[2048];                // 2 x (64 rows x 16 words) = 16 KB

    int nchunk = (nsel + 63) >> 6;          // <= 16
    ull S = 0ull;                           // lane w<16 holds suppressed-word w

    if (nchunk > 0) {
        ull r[16];
        // preload chunk 0 (rows are contiguous: chunk c = mrow[c*1024 .. +1023])
        #pragma unroll
        for (int k = 0; k < 16; ++k) r[k] = mrow[k * 64 + lane];
        #pragma unroll
        for (int k = 0; k < 16; ++k) sm[k * 64 + lane] = r[k];

        for (int c = 0; c < nchunk; ++c) {
            int cb = (c & 1) << 10;
            int nb = ((c + 1) & 1) << 10;
            bool more = (c + 1) < nchunk;
            if (more) {                      // issue next chunk's loads now
                #pragma unroll
                for (int k = 0; k < 16; ++k)
                    r[k] = mrow[(size_t)(c + 1) * 1024 + k * 64 + lane];
            }

            // ---- serial within-chunk greedy (word c only) ----
            int rmax = nsel - (c << 6); if (rmax > 64) rmax = 64;
            ull cur   = __shfl(S, c);        // current word c of S, broadcast
            ull kbits = 0ull;
            #pragma unroll 8
            for (int i = 0; i < rmax; ++i) {
                ull di  = sm[cb + (i << 4) + c];     // diag word, LDS broadcast (off-chain)
                ull sup = (cur >> i) & 1ull;
                cur   |= di & (sup - 1ull);          // sup==0 (kept) -> OR in row i's word c
                kbits |= (sup ^ 1ull) << i;
            }

            // ---- bulk-apply kept rows to future words (lanes c+1..15) ----
            ull kb = kbits;
            while (kb) {
                int i = __ffsll(kb) - 1;
                kb &= kb - 1ull;
                if (lane > c && lane < WORDS)
                    S |= sm[cb + (i << 4) + lane];   // independent reads, pipelined
            }
            if (lane == c) S = cur;                  // finalize word c

            if (more) {                      // publish next chunk to other LDS buffer
                #pragma unroll
                for (int k = 0; k < 16; ++k) sm[nb + k * 64 + lane] = r[k];
            }
        }
    }

    // ---- kept bitmap -> compact positions -> write packed rows ----
    int base_i = lane << 6;
    ull valid = 0ull;
    if (lane < WORDS) {
        int rem = nsel - base_i;
        if (rem > 0) valid = (rem >= 64) ? ~0ull : ((1ull << rem) - 1ull);
    }
    ull K = (~S) & valid;
    int cpc = __popcll(K);
    int x = cpc;
    for (int d = 1; d < 64; d <<= 1) {
        int y = __shfl_up(x, d);
        if (lane >= d) x += y;
    }
    int pos = x - cpc;                        // exclusive prefix of kept counts

    const float* rbase = rows + (size_t)bc * KTOP * 5;
    float* obase = out + (size_t)bc * KTOP * 5;
    for (int bit = 0; bit < 64; ++bit) {
        if ((K >> bit) & 1ull) {
            int i = base_i + bit;
            const float* rr = rbase + i * 5;
            float* oo = obase + pos * 5;
            oo[0] = rr[0]; oo[1] = rr[1]; oo[2] = rr[2]; oo[3] = rr[3]; oo[4] = rr[4];
            ++pos;
        }
    }
}

// ------------------------------- launcher -------------------------------
extern "C" void kernel_launch(void* const* d_in, const int* in_sizes, int n_in,
                              void* d_out, int out_size, void* d_ws, size_t ws_size,
                              hipStream_t stream) {
    (void)n_in; (void)ws_size;
    const float* loc   = (const float*)d_in[0];
    const float* conf  = (const float*)d_in[1];
    const float* prior = (const float*)d_in[2];
    const float* cth   = (const float*)d_in[3];
    const float* nth   = (const float*)d_in[4];
    float* out = (float*)d_out;

    int P   = in_sizes[2] / 4;
    int B   = in_sizes[0] / (4 * P);
    int C   = in_sizes[1] / (B * P);
    int Cfg = C - 1;
    int NBC = B * Cfg;

    // ---- carve workspace (256B aligned sections; 8B types first) ----
    char* base = (char*)d_ws;
    size_t off = 0;
    auto carve = [&](size_t bytes) { char* p = base + off; off = (off + bytes + 255) & ~(size_t)255; return p; };

    ull*      cand   = (ull*)     carve((size_t)NBC * CAP * 8);
    ull*      mask   = (ull*)     carve((size_t)NBC * ROWS * WORDS * 8);
    float*    scores = (float*)   carve((size_t)NBC * P * 4);
    float*    cs     = (float*)   carve((size_t)B * P * 4 * 4);
    float*    rows   = (float*)   carve((size_t)NBC * KTOP * 5 * 4);
    float*    bx1    = (float*)   carve((size_t)NBC * ROWS * 4);
    float*    by1    = (float*)   carve((size_t)NBC * ROWS * 4);
    float*    bx2    = (float*)   carve((size_t)NBC * ROWS * 4);
    float*    by2    = (float*)   carve((size_t)NBC * ROWS * 4);
    float*    bar    = (float*)   carve((size_t)NBC * ROWS * 4);
    unsigned* hist   = (unsigned*)carve((size_t)NBC * HB * 4 + (size_t)NBC * 4);  // hist + cnt contiguous
    unsigned* cnt    = hist + (size_t)NBC * HB;
    unsigned* pivot  = (unsigned*)carve((size_t)NBC * 4);
    int*      nselA  = (int*)     carve((size_t)NBC * 4);

    hipMemsetAsync(hist, 0, (size_t)NBC * HB * 4 + (size_t)NBC * 4, stream);
    hipMemsetAsync(out, 0, (size_t)out_size * 4, stream);

    int n1 = B * P;
    decode_kernel<<<(n1 + 255) / 256, 256, 0, stream>>>(loc, conf, prior, cth, scores, cs, hist, B, C, P);
    pivot_kernel<<<NBC, 1024, 0, stream>>>(hist, pivot);
    gather_kernel<<<dim3(NBC, 32), 256, 0, stream>>>(scores, pivot, cnt, cand, cth, P);
    sort_kernel<<<NBC, 1024, 0, stream>>>(cand, cnt, cs, rows, bx1, by1, bx2, by2, bar, nselA, P, Cfg);
    mask_kernel<<<dim3(NBC, ROWS / 64), 1024, 0, stream>>>(bx1, by1, bx2, by2, bar, nselA, nth, mask);
    reduce_pack_kernel<<<NBC, 64, 0, stream>>>(mask, nselA, rows, out);
}

// Round 4
// 440.463 us; speedup vs baseline: 1.8476x; 1.4511x over previous
//
#include <hip/hip_runtime.h>
#include <cstdint>
#include <cstddef>

typedef unsigned long long ull;

#define KTOP   1000
#define CAP    4096      // candidate gather capacity per (b,c)
#define HBITS  14
#define HB     (1 << HBITS)          // 16384 histogram bins (top-14 float bits)
#define HSHIFT (32 - HBITS)
#define ROWS   1024      // padded rank capacity (>= KTOP)
#define WORDS  16        // 1024 / 64 bitmask words per row
#define HCHUNK 16        // score chunks per (b,c) for the LDS histogram kernel

// ---------------- Kernel 1: softmax + SSD decode (pure streaming) ----------------
__global__ void decode_kernel(const float* __restrict__ loc,
                              const float* __restrict__ conf,
                              const float* __restrict__ prior,
                              float* __restrict__ scores,   // [B*Cfg][P]
                              float* __restrict__ cs,       // [B][P][4] center-size
                              int B, int C, int P) {
#pragma clang fp contract(off)
    int t = blockIdx.x * blockDim.x + threadIdx.x;
    if (t >= B * P) return;
    int b = t / P;
    int p = t - b * P;

    // softmax over class dim (C small)
    float x[8];
    float m = -INFINITY;
    for (int c = 0; c < C; ++c) {
        x[c] = conf[((size_t)b * C + c) * P + p];
        m = fmaxf(m, x[c]);
    }
    float sum = 0.f;
    for (int c = 0; c < C; ++c) {
        x[c] = expf(x[c] - m);
        sum += x[c];
    }
    for (int c = 1; c < C; ++c) {
        float v = x[c] / sum;
        int bc = b * (C - 1) + (c - 1);
        scores[(size_t)bc * P + p] = v;
    }

    // decode
    float l0 = loc[((size_t)b * 4 + 0) * P + p];
    float l1 = loc[((size_t)b * 4 + 1) * P + p];
    float l2 = loc[((size_t)b * 4 + 2) * P + p];
    float l3 = loc[((size_t)b * 4 + 3) * P + p];
    float pcx = prior[(size_t)p * 4 + 0];
    float pcy = prior[(size_t)p * 4 + 1];
    float pw  = prior[(size_t)p * 4 + 2];
    float ph  = prior[(size_t)p * 4 + 3];

    float cx = pcx + (l0 * 0.1f) * pw;
    float cy = pcy + (l1 * 0.1f) * ph;
    float w  = pw * expf(l2 * 0.2f);
    float h  = ph * expf(l3 * 0.2f);

    size_t o = ((size_t)b * P + p) * 4;
    cs[o + 0] = cx;
    cs[o + 1] = cy;
    cs[o + 2] = w;
    cs[o + 3] = h;
}

// ---------------- Kernel 1b: LDS-privatized score histogram ----------------
// Grid (NBC, HCHUNK). 16384 bins packed 2-per-u32 (16-bit halves; per-chunk
// counts <= chunk size < 65536 so the halves can't carry into each other).
// Sparse flush: only nonzero bins hit global atomics (~hundreds per block).
__global__ void __launch_bounds__(256)
hist_kernel(const float* __restrict__ scores,
            const float* __restrict__ cthp,
            unsigned* __restrict__ hist,     // [NBC][HB]
            int P) {
    __shared__ unsigned sh[HB / 2];          // 32 KB
    int bc  = blockIdx.x;
    int tid = threadIdx.x;
    float cth = *cthp;

    for (int i = tid; i < HB / 2; i += 256) sh[i] = 0u;
    __syncthreads();

    int chunk = (P + HCHUNK - 1) / HCHUNK;
    int lo = blockIdx.y * chunk;
    int hi = lo + chunk; if (hi > P) hi = P;
    const float* s = scores + (size_t)bc * P;
    for (int p = lo + tid; p < hi; p += 256) {
        float v = s[p];
        if (v >= cth) {
            unsigned bin = __float_as_uint(v) >> HSHIFT;
            atomicAdd(&sh[bin >> 1], (bin & 1u) ? 65536u : 1u);
        }
    }
    __syncthreads();

    unsigned* h = hist + (size_t)bc * HB;
    for (int i = tid; i < HB / 2; i += 256) {
        unsigned v = sh[i];
        if (v & 0xFFFFu)  atomicAdd(&h[2 * i],     v & 0xFFFFu);
        if (v >> 16)      atomicAdd(&h[2 * i + 1], v >> 16);
    }
}

// ---------------- Kernel 2: per-(b,c) pivot bin via parallel suffix scan ----------------
__global__ void __launch_bounds__(256)
pivot_kernel(const unsigned* __restrict__ hist, unsigned* __restrict__ pivot) {
    int bc  = blockIdx.x;
    int t   = threadIdx.x;
    const unsigned* h = hist + (size_t)bc * HB;
    __shared__ unsigned T[256];

    const int per = HB / 256;                // 64 bins per thread
    int base = t * per;
    unsigned S = 0;
    for (int i = 0; i < per; ++i) S += h[base + i];
    T[t] = S;
    __syncthreads();

    // inclusive suffix scan: T[t] = sum_{u>=t} S_u (8 Hillis-Steele steps)
    for (int d = 1; d < 256; d <<= 1) {
        unsigned add = (t + d < 256) ? T[t + d] : 0u;
        __syncthreads();
        T[t] += add;
        __syncthreads();
    }

    unsigned Tt = T[t];
    unsigned Tn = (t + 1 < 256) ? T[t + 1] : 0u;
    if (Tt >= (unsigned)KTOP && Tn < (unsigned)KTOP) {
        // threshold crossing lands in this thread's 64-bin segment
        unsigned cum = Tn;
        for (int i = per - 1; i >= 0; --i) {
            cum += h[base + i];
            if (cum >= (unsigned)KTOP) { pivot[bc] = (unsigned)(base + i); break; }
        }
    }
    if (t == 0 && T[0] < (unsigned)KTOP) pivot[bc] = 0u;   // fewer than KTOP valid: take all
}

// ---------------- Kernel 3: GPU-wide gather of candidates >= pivot ----------------
__global__ void gather_kernel(const float* __restrict__ scores,
                              const unsigned* __restrict__ pivot,
                              unsigned* __restrict__ cnt,
                              ull* __restrict__ cand,
                              const float* __restrict__ cthp, int P) {
    int bc = blockIdx.x;
    const float* s = scores + (size_t)bc * P;
    float cth = *cthp;
    unsigned pv = pivot[bc];
    int nchunk = gridDim.y;
    int chunk = (P + nchunk - 1) / nchunk;
    int lo = blockIdx.y * chunk;
    int hi = lo + chunk; if (hi > P) hi = P;
    for (int p = lo + threadIdx.x; p < hi; p += blockDim.x) {
        float v = s[p];
        if (v >= cth) {
            unsigned k = __float_as_uint(v);
            if ((k >> HSHIFT) >= pv) {
                unsigned pos = atomicAdd(&cnt[bc], 1u);
                if (pos < CAP)
                    cand[(size_t)bc * CAP + pos] = ((ull)k << 32) | (unsigned)(~(unsigned)p);
            }
        }
    }
}

// ---------------- Kernel 4: per-(b,c) bitonic sort + export sorted boxes ----------------
__global__ void __launch_bounds__(1024)
sort_kernel(const ull* __restrict__ cand,
            const unsigned* __restrict__ cnt,
            const float* __restrict__ cs,
            float* __restrict__ rows,      // [NBC][KTOP][5] score,cx,cy,w,h
            float* __restrict__ bx1, float* __restrict__ by1,
            float* __restrict__ bx2, float* __restrict__ by2,
            float* __restrict__ bar,       // SoA [NBC][ROWS]
            int* __restrict__ nselArr,
            int P, int Cfg) {
#pragma clang fp contract(off)
    int bc  = blockIdx.x;
    int b   = bc / Cfg;
    int tid = threadIdx.x;
    __shared__ ull sbuf[CAP];

    int M = (int)cnt[bc]; if (M > CAP) M = CAP;
    int nsel = M < KTOP ? M : KTOP;
    if (tid == 0) nselArr[bc] = nsel;

    int n = 1024;
    while (n < M) n <<= 1;
    for (int i = tid; i < n; i += 1024)
        sbuf[i] = (i < M) ? cand[(size_t)bc * CAP + i] : 0ull;
    __syncthreads();

    for (unsigned k = 2; k <= (unsigned)n; k <<= 1) {
        for (unsigned j = k >> 1; j > 0; j >>= 1) {
            for (unsigned i = tid; i < (unsigned)n; i += 1024) {
                unsigned ixj = i ^ j;
                if (ixj > i) {
                    bool up = ((i & k) == 0u);
                    ull a = sbuf[i], bb = sbuf[ixj];
                    if ((a > bb) == up) { sbuf[i] = bb; sbuf[ixj] = a; }
                }
            }
            __syncthreads();
        }
    }

    for (int r = tid; r < nsel; r += 1024) {
        ull e = sbuf[n - 1 - r];
        float sc = __uint_as_float((unsigned)(e >> 32));
        int idx = (int)(~(unsigned)e);
        const float* c4 = cs + ((size_t)b * P + idx) * 4;
        float cx = c4[0], cy = c4[1], w = c4[2], h = c4[3];
        float x1 = cx - w / 2.f, y1 = cy - h / 2.f;
        float x2 = cx + w / 2.f, y2 = cy + h / 2.f;
        size_t sb = (size_t)bc * ROWS + r;
        bx1[sb] = x1; by1[sb] = y1; bx2[sb] = x2; by2[sb] = y2;
        bar[sb] = fmaxf(x2 - x1, 0.f) * fmaxf(y2 - y1, 0.f);
        float* rr = rows + ((size_t)bc * KTOP + r) * 5;
        rr[0] = sc; rr[1] = cx; rr[2] = cy; rr[3] = w; rr[4] = h;
    }
}

// ---------------- Kernel 5: GPU-wide suppression bitmask matrix ----------------
__global__ void __launch_bounds__(1024)
mask_kernel(const float* __restrict__ bx1, const float* __restrict__ by1,
            const float* __restrict__ bx2, const float* __restrict__ by2,
            const float* __restrict__ bar,
            const int* __restrict__ nselArr,
            const float* __restrict__ nthp,
            ull* __restrict__ mask) {       // [NBC][ROWS][WORDS]
#pragma clang fp contract(off)
    int bc   = blockIdx.x;
    int tile = blockIdx.y;                  // 16 tiles x 64 rows
    int tid  = threadIdx.x;
    int nsel = nselArr[bc];
    float nth = *nthp;

    __shared__ float sx1[ROWS], sy1[ROWS], sx2[ROWS], sy2[ROWS], sar[ROWS];
    size_t sb = (size_t)bc * ROWS;
    if (tid < nsel) {
        sx1[tid] = bx1[sb + tid]; sy1[tid] = by1[sb + tid];
        sx2[tid] = bx2[sb + tid]; sy2[tid] = by2[sb + tid];
        sar[tid] = bar[sb + tid];
    }
    __syncthreads();

    int i = tile * 64 + (tid >> 4);
    int w = tid & 15;
    if (i >= nsel) return;

    float xi1 = sx1[i], yi1 = sy1[i], xi2 = sx2[i], yi2 = sy2[i], ai = sar[i];
    ull bits = 0ull;
    int j0 = w << 6;
    // rotate start by w*4 to break the 16-way LDS bank aliasing across word-groups
    for (int jj0 = 0; jj0 < 64; ++jj0) {
        int jj = (jj0 + (w << 2)) & 63;
        int j = j0 + jj;
        if (j > i && j < nsel) {
            float ww = fmaxf(fminf(xi2, sx2[j]) - fmaxf(xi1, sx1[j]), 0.f);
            float hh = fmaxf(fminf(yi2, sy2[j]) - fmaxf(yi1, sy1[j]), 0.f);
            float inter = ww * hh;
            float uni = ai + sar[j] - inter;
            float iou = inter / fmaxf(uni, 1e-12f);
            if (iou > nth) bits |= 1ull << jj;
        }
    }
    mask[(((size_t)bc * ROWS + i) << 4) + w] = bits;
}

// ---------------- Kernel 6: chunked serial bit-OR reduction + compact + write ----------------
__global__ void __launch_bounds__(64)
reduce_pack_kernel(const ull* __restrict__ mask,
                   const int* __restrict__ nselArr,
                   const float* __restrict__ rows,
                   float* __restrict__ out) {
    int bc   = blockIdx.x;
    int lane = threadIdx.x;                 // 64 threads = 1 wave
    int nsel = nselArr[bc];
    const ull* mrow = mask + ((size_t)bc * ROWS << 4);

    __shared__ ull sm[2048];                // 2 x (64 rows x 16 words) = 16 KB

    int nchunk = (nsel + 63) >> 6;          // <= 16
    ull S = 0ull;                           // lane w<16 holds suppressed-word w

    if (nchunk > 0) {
        ull r[16];
        #pragma unroll
        for (int k = 0; k < 16; ++k) r[k] = mrow[k * 64 + lane];
        #pragma unroll
        for (int k = 0; k < 16; ++k) sm[k * 64 + lane] = r[k];

        for (int c = 0; c < nchunk; ++c) {
            int cb = (c & 1) << 10;
            int nb = ((c + 1) & 1) << 10;
            bool more = (c + 1) < nchunk;
            if (more) {
                #pragma unroll
                for (int k = 0; k < 16; ++k)
                    r[k] = mrow[(size_t)(c + 1) * 1024 + k * 64 + lane];
            }

            int rmax = nsel - (c << 6); if (rmax > 64) rmax = 64;
            ull cur   = __shfl(S, c);
            ull kbits = 0ull;
            #pragma unroll 8
            for (int i = 0; i < rmax; ++i) {
                ull di  = sm[cb + (i << 4) + c];
                ull sup = (cur >> i) & 1ull;
                cur   |= di & (sup - 1ull);
                kbits |= (sup ^ 1ull) << i;
            }

            ull kb = kbits;
            while (kb) {
                int i = __ffsll(kb) - 1;
                kb &= kb - 1ull;
                if (lane > c && lane < WORDS)
                    S |= sm[cb + (i << 4) + lane];
            }
            if (lane == c) S = cur;

            if (more) {
                #pragma unroll
                for (int k = 0; k < 16; ++k) sm[nb + k * 64 + lane] = r[k];
            }
        }
    }

    int base_i = lane << 6;
    ull valid = 0ull;
    if (lane < WORDS) {
        int rem = nsel - base_i;
        if (rem > 0) valid = (rem >= 64) ? ~0ull : ((1ull << rem) - 1ull);
    }
    ull K = (~S) & valid;
    int cpc = __popcll(K);
    int x = cpc;
    for (int d = 1; d < 64; d <<= 1) {
        int y = __shfl_up(x, d);
        if (lane >= d) x += y;
    }
    int pos = x - cpc;

    const float* rbase = rows + (size_t)bc * KTOP * 5;
    float* obase = out + (size_t)bc * KTOP * 5;
    for (int bit = 0; bit < 64; ++bit) {
        if ((K >> bit) & 1ull) {
            int i = base_i + bit;
            const float* rr = rbase + i * 5;
            float* oo = obase + pos * 5;
            oo[0] = rr[0]; oo[1] = rr[1]; oo[2] = rr[2]; oo[3] = rr[3]; oo[4] = rr[4];
            ++pos;
        }
    }
}

// ------------------------------- launcher -------------------------------
extern "C" void kernel_launch(void* const* d_in, const int* in_sizes, int n_in,
                              void* d_out, int out_size, void* d_ws, size_t ws_size,
                              hipStream_t stream) {
    (void)n_in; (void)ws_size;
    const float* loc   = (const float*)d_in[0];
    const float* conf  = (const float*)d_in[1];
    const float* prior = (const float*)d_in[2];
    const float* cth   = (const float*)d_in[3];
    const float* nth   = (const float*)d_in[4];
    float* out = (float*)d_out;

    int P   = in_sizes[2] / 4;
    int B   = in_sizes[0] / (4 * P);
    int C   = in_sizes[1] / (B * P);
    int Cfg = C - 1;
    int NBC = B * Cfg;

    // ---- carve workspace (256B aligned sections; 8B types first) ----
    char* base = (char*)d_ws;
    size_t off = 0;
    auto carve = [&](size_t bytes) { char* p = base + off; off = (off + bytes + 255) & ~(size_t)255; return p; };

    ull*      cand   = (ull*)     carve((size_t)NBC * CAP * 8);
    ull*      mask   = (ull*)     carve((size_t)NBC * ROWS * WORDS * 8);
    float*    scores = (float*)   carve((size_t)NBC * P * 4);
    float*    cs     = (float*)   carve((size_t)B * P * 4 * 4);
    float*    rows   = (float*)   carve((size_t)NBC * KTOP * 5 * 4);
    float*    bx1    = (float*)   carve((size_t)NBC * ROWS * 4);
    float*    by1    = (float*)   carve((size_t)NBC * ROWS * 4);
    float*    bx2    = (float*)   carve((size_t)NBC * ROWS * 4);
    float*    by2    = (float*)   carve((size_t)NBC * ROWS * 4);
    float*    bar    = (float*)   carve((size_t)NBC * ROWS * 4);
    unsigned* hist   = (unsigned*)carve((size_t)NBC * HB * 4 + (size_t)NBC * 4);  // hist + cnt contiguous
    unsigned* cnt    = hist + (size_t)NBC * HB;
    unsigned* pivot  = (unsigned*)carve((size_t)NBC * 4);
    int*      nselA  = (int*)     carve((size_t)NBC * 4);

    hipMemsetAsync(hist, 0, (size_t)NBC * HB * 4 + (size_t)NBC * 4, stream);
    hipMemsetAsync(out, 0, (size_t)out_size * 4, stream);

    int n1 = B * P;
    decode_kernel<<<(n1 + 255) / 256, 256, 0, stream>>>(loc, conf, prior, scores, cs, B, C, P);
    hist_kernel<<<dim3(NBC, HCHUNK), 256, 0, stream>>>(scores, cth, hist, P);
    pivot_kernel<<<NBC, 256, 0, stream>>>(hist, pivot);
    gather_kernel<<<dim3(NBC, 32), 256, 0, stream>>>(scores, pivot, cnt, cand, cth, P);
    sort_kernel<<<NBC, 1024, 0, stream>>>(cand, cnt, cs, rows, bx1, by1, bx2, by2, bar, nselA, P, Cfg);
    mask_kernel<<<dim3(NBC, ROWS / 64), 1024, 0, stream>>>(bx1, by1, bx2, by2, bar, nselA, nth, mask);
    reduce_pack_kernel<<<NBC, 64, 0, stream>>>(mask, nselA, rows, out);
}

// Round 5
// 438.939 us; speedup vs baseline: 1.8540x; 1.0035x over previous
//
#include <hip/hip_runtime.h>
#include <cstdint>
#include <cstddef>

typedef unsigned long long ull;

#define KTOP   1000
#define CAP    4096      // candidate gather capacity per (b,c)
#define HBITS  14
#define HB     (1 << HBITS)          // 16384 histogram bins (top-14 float bits)
#define HSHIFT (32 - HBITS)
#define ROWS   1024      // padded rank capacity (>= KTOP)
#define WORDS  16        // 1024 / 64 bitmask words per row
#define HCHUNK 16        // score chunks per (b,c) for the LDS histogram kernel

// ---------------- Kernel 1: softmax + SSD decode (pure streaming) ----------------
__global__ void decode_kernel(const float* __restrict__ loc,
                              const float* __restrict__ conf,
                              const float* __restrict__ prior,
                              float* __restrict__ scores,   // [B*Cfg][P]
                              float* __restrict__ cs,       // [B][P][4] center-size
                              int B, int C, int P) {
#pragma clang fp contract(off)
    int t = blockIdx.x * blockDim.x + threadIdx.x;
    if (t >= B * P) return;
    int b = t / P;
    int p = t - b * P;

    // softmax over class dim (C small)
    float x[8];
    float m = -INFINITY;
    for (int c = 0; c < C; ++c) {
        x[c] = conf[((size_t)b * C + c) * P + p];
        m = fmaxf(m, x[c]);
    }
    float sum = 0.f;
    for (int c = 0; c < C; ++c) {
        x[c] = expf(x[c] - m);
        sum += x[c];
    }
    for (int c = 1; c < C; ++c) {
        float v = x[c] / sum;
        int bc = b * (C - 1) + (c - 1);
        scores[(size_t)bc * P + p] = v;
    }

    // decode
    float l0 = loc[((size_t)b * 4 + 0) * P + p];
    float l1 = loc[((size_t)b * 4 + 1) * P + p];
    float l2 = loc[((size_t)b * 4 + 2) * P + p];
    float l3 = loc[((size_t)b * 4 + 3) * P + p];
    float pcx = prior[(size_t)p * 4 + 0];
    float pcy = prior[(size_t)p * 4 + 1];
    float pw  = prior[(size_t)p * 4 + 2];
    float ph  = prior[(size_t)p * 4 + 3];

    float cx = pcx + (l0 * 0.1f) * pw;
    float cy = pcy + (l1 * 0.1f) * ph;
    float w  = pw * expf(l2 * 0.2f);
    float h  = ph * expf(l3 * 0.2f);

    size_t o = ((size_t)b * P + p) * 4;
    cs[o + 0] = cx;
    cs[o + 1] = cy;
    cs[o + 2] = w;
    cs[o + 3] = h;
}

// ---------------- Kernel 1b: LDS-privatized score histogram ----------------
__global__ void __launch_bounds__(256)
hist_kernel(const float* __restrict__ scores,
            const float* __restrict__ cthp,
            unsigned* __restrict__ hist,     // [NBC][HB]
            int P) {
    __shared__ unsigned sh[HB / 2];          // 32 KB (16-bit packed counters)
    int bc  = blockIdx.x;
    int tid = threadIdx.x;
    float cth = *cthp;

    for (int i = tid; i < HB / 2; i += 256) sh[i] = 0u;
    __syncthreads();

    int chunk = (P + HCHUNK - 1) / HCHUNK;
    int lo = blockIdx.y * chunk;
    int hi = lo + chunk; if (hi > P) hi = P;
    const float* s = scores + (size_t)bc * P;
    for (int p = lo + tid; p < hi; p += 256) {
        float v = s[p];
        if (v >= cth) {
            unsigned bin = __float_as_uint(v) >> HSHIFT;
            atomicAdd(&sh[bin >> 1], (bin & 1u) ? 65536u : 1u);
        }
    }
    __syncthreads();

    unsigned* h = hist + (size_t)bc * HB;
    for (int i = tid; i < HB / 2; i += 256) {
        unsigned v = sh[i];
        if (v & 0xFFFFu)  atomicAdd(&h[2 * i],     v & 0xFFFFu);
        if (v >> 16)      atomicAdd(&h[2 * i + 1], v >> 16);
    }
}

// ---------------- Kernel 2: per-(b,c) pivot bin via parallel suffix scan ----------------
__global__ void __launch_bounds__(256)
pivot_kernel(const unsigned* __restrict__ hist, unsigned* __restrict__ pivot) {
    int bc  = blockIdx.x;
    int t   = threadIdx.x;
    const unsigned* h = hist + (size_t)bc * HB;
    __shared__ unsigned T[256];

    const int per = HB / 256;                // 64 bins per thread
    int base = t * per;
    unsigned S = 0;
    for (int i = 0; i < per; ++i) S += h[base + i];
    T[t] = S;
    __syncthreads();

    for (int d = 1; d < 256; d <<= 1) {
        unsigned add = (t + d < 256) ? T[t + d] : 0u;
        __syncthreads();
        T[t] += add;
        __syncthreads();
    }

    unsigned Tt = T[t];
    unsigned Tn = (t + 1 < 256) ? T[t + 1] : 0u;
    if (Tt >= (unsigned)KTOP && Tn < (unsigned)KTOP) {
        unsigned cum = Tn;
        for (int i = per - 1; i >= 0; --i) {
            cum += h[base + i];
            if (cum >= (unsigned)KTOP) { pivot[bc] = (unsigned)(base + i); break; }
        }
    }
    if (t == 0 && T[0] < (unsigned)KTOP) pivot[bc] = 0u;   // fewer than KTOP valid: take all
}

// ---------------- Kernel 3: gather with wave-aggregated allocation ----------------
// One returning atomic per wave (not per candidate): ballot the predicate,
// leader lane reserves popcount slots, lanes place at base + intra-wave rank.
// Buffer order is irrelevant (sort_kernel re-sorts).
__global__ void gather_kernel(const float* __restrict__ scores,
                              const unsigned* __restrict__ pivot,
                              unsigned* __restrict__ cnt,
                              ull* __restrict__ cand,
                              const float* __restrict__ cthp, int P) {
    int bc = blockIdx.x;
    const float* s = scores + (size_t)bc * P;
    float cth = *cthp;
    unsigned pv = pivot[bc];
    int nchunk = gridDim.y;
    int chunk = (P + nchunk - 1) / nchunk;
    int lo = blockIdx.y * chunk;
    int hi = lo + chunk; if (hi > P) hi = P;
    int lane = threadIdx.x & 63;
    ull* cb = cand + (size_t)bc * CAP;

    for (int p = lo + threadIdx.x; p < hi; p += blockDim.x) {
        float v = s[p];
        unsigned k = __float_as_uint(v);
        bool ok = (v >= cth) && ((k >> HSHIFT) >= pv);
        ull ball = __ballot(ok);
        if (ball) {
            int leader = __ffsll(ball) - 1;
            unsigned base = 0;
            if (lane == leader) base = atomicAdd(&cnt[bc], (unsigned)__popcll(ball));
            base = (unsigned)__shfl((int)base, leader);
            if (ok) {
                unsigned pos = base + (unsigned)__popcll(ball & ((1ull << lane) - 1ull));
                if (pos < CAP)
                    cb[pos] = ((ull)k << 32) | (unsigned)(~(unsigned)p);
            }
        }
    }
}

// ---------------- Kernel 4: per-(b,c) bitonic sort + export sorted boxes ----------------
__global__ void __launch_bounds__(1024)
sort_kernel(const ull* __restrict__ cand,
            const unsigned* __restrict__ cnt,
            const float* __restrict__ cs,
            float* __restrict__ rows,      // [NBC][KTOP][5] score,cx,cy,w,h
            float* __restrict__ bx1, float* __restrict__ by1,
            float* __restrict__ bx2, float* __restrict__ by2,
            float* __restrict__ bar,       // SoA [NBC][ROWS]
            int* __restrict__ nselArr,
            int P, int Cfg) {
#pragma clang fp contract(off)
    int bc  = blockIdx.x;
    int b   = bc / Cfg;
    int tid = threadIdx.x;
    __shared__ ull sbuf[CAP];

    int M = (int)cnt[bc]; if (M > CAP) M = CAP;
    int nsel = M < KTOP ? M : KTOP;
    if (tid == 0) nselArr[bc] = nsel;

    int n = 1024;
    while (n < M) n <<= 1;
    for (int i = tid; i < n; i += 1024)
        sbuf[i] = (i < M) ? cand[(size_t)bc * CAP + i] : 0ull;
    __syncthreads();

    for (unsigned k = 2; k <= (unsigned)n; k <<= 1) {
        for (unsigned j = k >> 1; j > 0; j >>= 1) {
            for (unsigned i = tid; i < (unsigned)n; i += 1024) {
                unsigned ixj = i ^ j;
                if (ixj > i) {
                    bool up = ((i & k) == 0u);
                    ull a = sbuf[i], bb = sbuf[ixj];
                    if ((a > bb) == up) { sbuf[i] = bb; sbuf[ixj] = a; }
                }
            }
            __syncthreads();
        }
    }

    for (int r = tid; r < nsel; r += 1024) {
        ull e = sbuf[n - 1 - r];
        float sc = __uint_as_float((unsigned)(e >> 32));
        int idx = (int)(~(unsigned)e);
        const float* c4 = cs + ((size_t)b * P + idx) * 4;
        float cx = c4[0], cy = c4[1], w = c4[2], h = c4[3];
        float x1 = cx - w / 2.f, y1 = cy - h / 2.f;
        float x2 = cx + w / 2.f, y2 = cy + h / 2.f;
        size_t sb = (size_t)bc * ROWS + r;
        bx1[sb] = x1; by1[sb] = y1; bx2[sb] = x2; by2[sb] = y2;
        bar[sb] = fmaxf(x2 - x1, 0.f) * fmaxf(y2 - y1, 0.f);
        float* rr = rows + ((size_t)bc * KTOP + r) * 5;
        rr[0] = sc; rr[1] = cx; rr[2] = cy; rr[3] = w; rr[4] = h;
    }
}

// ---------------- Kernel 5: GPU-wide suppression bitmask matrix ----------------
__global__ void __launch_bounds__(1024)
mask_kernel(const float* __restrict__ bx1, const float* __restrict__ by1,
            const float* __restrict__ bx2, const float* __restrict__ by2,
            const float* __restrict__ bar,
            const int* __restrict__ nselArr,
            const float* __restrict__ nthp,
            ull* __restrict__ mask) {       // [NBC][ROWS][WORDS]
#pragma clang fp contract(off)
    int bc   = blockIdx.x;
    int tile = blockIdx.y;                  // 16 tiles x 64 rows
    int tid  = threadIdx.x;
    int nsel = nselArr[bc];
    float nth = *nthp;

    __shared__ float sx1[ROWS], sy1[ROWS], sx2[ROWS], sy2[ROWS], sar[ROWS];
    size_t sb = (size_t)bc * ROWS;
    if (tid < nsel) {
        sx1[tid] = bx1[sb + tid]; sy1[tid] = by1[sb + tid];
        sx2[tid] = bx2[sb + tid]; sy2[tid] = by2[sb + tid];
        sar[tid] = bar[sb + tid];
    }
    __syncthreads();

    int i = tile * 64 + (tid >> 4);
    int w = tid & 15;
    if (i >= nsel) return;

    float xi1 = sx1[i], yi1 = sy1[i], xi2 = sx2[i], yi2 = sy2[i], ai = sar[i];
    ull bits = 0ull;
    int j0 = w << 6;
    for (int jj0 = 0; jj0 < 64; ++jj0) {
        int jj = (jj0 + (w << 2)) & 63;
        int j = j0 + jj;
        if (j > i && j < nsel) {
            float ww = fmaxf(fminf(xi2, sx2[j]) - fmaxf(xi1, sx1[j]), 0.f);
            float hh = fmaxf(fminf(yi2, sy2[j]) - fmaxf(yi1, sy1[j]), 0.f);
            float inter = ww * hh;
            float uni = ai + sar[j] - inter;
            float iou = inter / fmaxf(uni, 1e-12f);
            if (iou > nth) bits |= 1ull << jj;
        }
    }
    mask[(((size_t)bc * ROWS + i) << 4) + w] = bits;
}

// ---------------- Kernel 6: chunked serial bit-OR reduction + compact + write ----------------
__global__ void __launch_bounds__(64)
reduce_pack_kernel(const ull* __restrict__ mask,
                   const int* __restrict__ nselArr,
                   const float* __restrict__ rows,
                   float* __restrict__ out) {
    int bc   = blockIdx.x;
    int lane = threadIdx.x;                 // 64 threads = 1 wave
    int nsel = nselArr[bc];
    const ull* mrow = mask + ((size_t)bc * ROWS << 4);

    __shared__ ull sm[2048];                // 2 x (64 rows x 16 words) = 16 KB

    int nchunk = (nsel + 63) >> 6;          // <= 16
    ull S = 0ull;                           // lane w<16 holds suppressed-word w

    if (nchunk > 0) {
        ull r[16];
        #pragma unroll
        for (int k = 0; k < 16; ++k) r[k] = mrow[k * 64 + lane];
        #pragma unroll
        for (int k = 0; k < 16; ++k) sm[k * 64 + lane] = r[k];

        for (int c = 0; c < nchunk; ++c) {
            int cb = (c & 1) << 10;
            int nb = ((c + 1) & 1) << 10;
            bool more = (c + 1) < nchunk;
            if (more) {
                #pragma unroll
                for (int k = 0; k < 16; ++k)
                    r[k] = mrow[(size_t)(c + 1) * 1024 + k * 64 + lane];
            }

            int rmax = nsel - (c << 6); if (rmax > 64) rmax = 64;
            ull cur   = __shfl(S, c);
            ull kbits = 0ull;
            #pragma unroll 8
            for (int i = 0; i < rmax; ++i) {
                ull di  = sm[cb + (i << 4) + c];
                ull sup = (cur >> i) & 1ull;
                cur   |= di & (sup - 1ull);
                kbits |= (sup ^ 1ull) << i;
            }

            ull kb = kbits;
            while (kb) {
                int i = __ffsll(kb) - 1;
                kb &= kb - 1ull;
                if (lane > c && lane < WORDS)
                    S |= sm[cb + (i << 4) + lane];
            }
            if (lane == c) S = cur;

            if (more) {
                #pragma unroll
                for (int k = 0; k < 16; ++k) sm[nb + k * 64 + lane] = r[k];
            }
        }
    }

    int base_i = lane << 6;
    ull valid = 0ull;
    if (lane < WORDS) {
        int rem = nsel - base_i;
        if (rem > 0) valid = (rem >= 64) ? ~0ull : ((1ull << rem) - 1ull);
    }
    ull K = (~S) & valid;
    int cpc = __popcll(K);
    int x = cpc;
    for (int d = 1; d < 64; d <<= 1) {
        int y = __shfl_up(x, d);
        if (lane >= d) x += y;
    }
    int pos = x - cpc;

    const float* rbase = rows + (size_t)bc * KTOP * 5;
    float* obase = out + (size_t)bc * KTOP * 5;
    for (int bit = 0; bit < 64; ++bit) {
        if ((K >> bit) & 1ull) {
            int i = base_i + bit;
            const float* rr = rbase + i * 5;
            float* oo = obase + pos * 5;
            oo[0] = rr[0]; oo[1] = rr[1]; oo[2] = rr[2]; oo[3] = rr[3]; oo[4] = rr[4];
            ++pos;
        }
    }
}

// ------------------------------- launcher -------------------------------
extern "C" void kernel_launch(void* const* d_in, const int* in_sizes, int n_in,
                              void* d_out, int out_size, void* d_ws, size_t ws_size,
                              hipStream_t stream) {
    (void)n_in; (void)ws_size;
    const float* loc   = (const float*)d_in[0];
    const float* conf  = (const float*)d_in[1];
    const float* prior = (const float*)d_in[2];
    const float* cth   = (const float*)d_in[3];
    const float* nth   = (const float*)d_in[4];
    float* out = (float*)d_out;

    int P   = in_sizes[2] / 4;
    int B   = in_sizes[0] / (4 * P);
    int C   = in_sizes[1] / (B * P);
    int Cfg = C - 1;
    int NBC = B * Cfg;

    // ---- carve workspace (256B aligned sections; 8B types first) ----
    char* base = (char*)d_ws;
    size_t off = 0;
    auto carve = [&](size_t bytes) { char* p = base + off; off = (off + bytes + 255) & ~(size_t)255; return p; };

    ull*      cand   = (ull*)     carve((size_t)NBC * CAP * 8);
    ull*      mask   = (ull*)     carve((size_t)NBC * ROWS * WORDS * 8);
    float*    scores = (float*)   carve((size_t)NBC * P * 4);
    float*    cs     = (float*)   carve((size_t)B * P * 4 * 4);
    float*    rows   = (float*)   carve((size_t)NBC * KTOP * 5 * 4);
    float*    bx1    = (float*)   carve((size_t)NBC * ROWS * 4);
    float*    by1    = (float*)   carve((size_t)NBC * ROWS * 4);
    float*    bx2    = (float*)   carve((size_t)NBC * ROWS * 4);
    float*    by2    = (float*)   carve((size_t)NBC * ROWS * 4);
    float*    bar    = (float*)   carve((size_t)NBC * ROWS * 4);
    unsigned* hist   = (unsigned*)carve((size_t)NBC * HB * 4 + (size_t)NBC * 4);  // hist + cnt contiguous
    unsigned* cnt    = hist + (size_t)NBC * HB;
    unsigned* pivot  = (unsigned*)carve((size_t)NBC * 4);
    int*      nselA  = (int*)     carve((size_t)NBC * 4);

    hipMemsetAsync(hist, 0, (size_t)NBC * HB * 4 + (size_t)NBC * 4, stream);
    hipMemsetAsync(out, 0, (size_t)out_size * 4, stream);

    int n1 = B * P;
    decode_kernel<<<(n1 + 255) / 256, 256, 0, stream>>>(loc, conf, prior, scores, cs, B, C, P);
    hist_kernel<<<dim3(NBC, HCHUNK), 256, 0, stream>>>(scores, cth, hist, P);
    pivot_kernel<<<NBC, 256, 0, stream>>>(hist, pivot);
    gather_kernel<<<dim3(NBC, 32), 256, 0, stream>>>(scores, pivot, cnt, cand, cth, P);
    sort_kernel<<<NBC, 1024, 0, stream>>>(cand, cnt, cs, rows, bx1, by1, bx2, by2, bar, nselA, P, Cfg);
    mask_kernel<<<dim3(NBC, ROWS / 64), 1024, 0, stream>>>(bx1, by1, bx2, by2, bar, nselA, nth, mask);
    reduce_pack_kernel<<<NBC, 64, 0, stream>>>(mask, nselA, rows, out);
}

// Round 6
// 293.097 us; speedup vs baseline: 2.7766x; 1.4976x over previous
//
#include <hip/hip_runtime.h>
#include <cstdint>
#include <cstddef>

typedef unsigned long long ull;

#define KTOP   1000
#define CAP    4096      // candidate gather capacity per (b,c)
#define HBITS  14
#define HB     (1 << HBITS)          // 16384 histogram bins (top-14 float bits)
#define HSHIFT (32 - HBITS)
#define ROWS   1024      // padded rank capacity (>= KTOP)
#define WORDS  16        // 1024 / 64 bitmask words per row
#define HCHUNK 16        // score chunks per (b,c) for the LDS histogram kernel

// ---------------- Kernel 1: softmax + SSD decode (pure streaming) ----------------
__global__ void decode_kernel(const float* __restrict__ loc,
                              const float* __restrict__ conf,
                              const float* __restrict__ prior,
                              float* __restrict__ scores,   // [B*Cfg][P]
                              float* __restrict__ cs,       // [B][P][4] center-size
                              int B, int C, int P) {
#pragma clang fp contract(off)
    int t = blockIdx.x * blockDim.x + threadIdx.x;
    if (t >= B * P) return;
    int b = t / P;
    int p = t - b * P;

    // softmax over class dim (C small)
    float x[8];
    float m = -INFINITY;
    for (int c = 0; c < C; ++c) {
        x[c] = conf[((size_t)b * C + c) * P + p];
        m = fmaxf(m, x[c]);
    }
    float sum = 0.f;
    for (int c = 0; c < C; ++c) {
        x[c] = expf(x[c] - m);
        sum += x[c];
    }
    for (int c = 1; c < C; ++c) {
        float v = x[c] / sum;
        int bc = b * (C - 1) + (c - 1);
        scores[(size_t)bc * P + p] = v;
    }

    // decode
    float l0 = loc[((size_t)b * 4 + 0) * P + p];
    float l1 = loc[((size_t)b * 4 + 1) * P + p];
    float l2 = loc[((size_t)b * 4 + 2) * P + p];
    float l3 = loc[((size_t)b * 4 + 3) * P + p];
    float pcx = prior[(size_t)p * 4 + 0];
    float pcy = prior[(size_t)p * 4 + 1];
    float pw  = prior[(size_t)p * 4 + 2];
    float ph  = prior[(size_t)p * 4 + 3];

    float cx = pcx + (l0 * 0.1f) * pw;
    float cy = pcy + (l1 * 0.1f) * ph;
    float w  = pw * expf(l2 * 0.2f);
    float h  = ph * expf(l3 * 0.2f);

    size_t o = ((size_t)b * P + p) * 4;
    cs[o + 0] = cx;
    cs[o + 1] = cy;
    cs[o + 2] = w;
    cs[o + 3] = h;
}

// ---------------- Kernel 1b: LDS-privatized score histogram ----------------
__global__ void __launch_bounds__(256)
hist_kernel(const float* __restrict__ scores,
            const float* __restrict__ cthp,
            unsigned* __restrict__ hist,     // [NBC][HB]
            int P) {
    __shared__ unsigned sh[HB / 2];          // 32 KB (16-bit packed counters)
    int bc  = blockIdx.x;
    int tid = threadIdx.x;
    float cth = *cthp;

    for (int i = tid; i < HB / 2; i += 256) sh[i] = 0u;
    __syncthreads();

    int chunk = (P + HCHUNK - 1) / HCHUNK;
    int lo = blockIdx.y * chunk;
    int hi = lo + chunk; if (hi > P) hi = P;
    const float* s = scores + (size_t)bc * P;
    for (int p = lo + tid; p < hi; p += 256) {
        float v = s[p];
        if (v >= cth) {
            unsigned bin = __float_as_uint(v) >> HSHIFT;
            atomicAdd(&sh[bin >> 1], (bin & 1u) ? 65536u : 1u);
        }
    }
    __syncthreads();

    unsigned* h = hist + (size_t)bc * HB;
    for (int i = tid; i < HB / 2; i += 256) {
        unsigned v = sh[i];
        if (v & 0xFFFFu)  atomicAdd(&h[2 * i],     v & 0xFFFFu);
        if (v >> 16)      atomicAdd(&h[2 * i + 1], v >> 16);
    }
}

// ---------------- Kernel 2: per-(b,c) pivot bin via parallel suffix scan ----------------
__global__ void __launch_bounds__(256)
pivot_kernel(const unsigned* __restrict__ hist, unsigned* __restrict__ pivot) {
    int bc  = blockIdx.x;
    int t   = threadIdx.x;
    const unsigned* h = hist + (size_t)bc * HB;
    __shared__ unsigned T[256];

    const int per = HB / 256;                // 64 bins per thread
    int base = t * per;
    unsigned S = 0;
    for (int i = 0; i < per; ++i) S += h[base + i];
    T[t] = S;
    __syncthreads();

    for (int d = 1; d < 256; d <<= 1) {
        unsigned add = (t + d < 256) ? T[t + d] : 0u;
        __syncthreads();
        T[t] += add;
        __syncthreads();
    }

    unsigned Tt = T[t];
    unsigned Tn = (t + 1 < 256) ? T[t + 1] : 0u;
    if (Tt >= (unsigned)KTOP && Tn < (unsigned)KTOP) {
        unsigned cum = Tn;
        for (int i = per - 1; i >= 0; --i) {
            cum += h[base + i];
            if (cum >= (unsigned)KTOP) { pivot[bc] = (unsigned)(base + i); break; }
        }
    }
    if (t == 0 && T[0] < (unsigned)KTOP) pivot[bc] = 0u;   // fewer than KTOP valid: take all
}

// ---------------- Kernel 3: gather with BLOCK-aggregated allocation ----------------
// Phase 1: count candidates per thread; block-wide exclusive scan (shfl + LDS);
// ONE global atomic per block (32 per cnt[bc] address vs ~1650 for per-wave).
// Phase 2: re-scan the L2-hot chunk, write at base + thread prefix.
__global__ void __launch_bounds__(256)
gather_kernel(const float* __restrict__ scores,
              const unsigned* __restrict__ pivot,
              unsigned* __restrict__ cnt,
              ull* __restrict__ cand,
              const float* __restrict__ cthp, int P) {
    __shared__ unsigned wsum[4];
    __shared__ unsigned s_base;
    int bc = blockIdx.x;
    const float* s = scores + (size_t)bc * P;
    float cth = *cthp;
    unsigned pv = pivot[bc];
    int nchunk = gridDim.y;
    int chunk = (P + nchunk - 1) / nchunk;
    int lo = blockIdx.y * chunk;
    int hi = lo + chunk; if (hi > P) hi = P;
    int tid  = threadIdx.x;
    int lane = tid & 63;
    int wid  = tid >> 6;

    // phase 1: count
    unsigned mycnt = 0;
    for (int p = lo + tid; p < hi; p += 256) {
        float v = s[p];
        unsigned k = __float_as_uint(v);
        if (v >= cth && (k >> HSHIFT) >= pv) ++mycnt;
    }
    // wave-inclusive prefix
    unsigned x = mycnt;
    for (int d = 1; d < 64; d <<= 1) {
        unsigned y = (unsigned)__shfl_up((int)x, d);
        if (lane >= d) x += y;
    }
    if (lane == 63) wsum[wid] = x;
    __syncthreads();
    if (tid == 0) {
        unsigned tot = 0;
        for (int w = 0; w < 4; ++w) { unsigned t2 = wsum[w]; wsum[w] = tot; tot += t2; }
        s_base = tot ? atomicAdd(&cnt[bc], tot) : 0u;
    }
    __syncthreads();
    unsigned off = s_base + wsum[wid] + (x - mycnt);

    // phase 2: write (chunk is L2-hot from phase 1)
    ull* cb = cand + (size_t)bc * CAP;
    for (int p = lo + tid; p < hi; p += 256) {
        float v = s[p];
        unsigned k = __float_as_uint(v);
        if (v >= cth && (k >> HSHIFT) >= pv) {
            if (off < CAP)
                cb[off] = ((ull)k << 32) | (unsigned)(~(unsigned)p);
            ++off;
        }
    }
}

// ---------------- Kernel 4: per-(b,c) bitonic sort + export sorted boxes ----------------
__global__ void __launch_bounds__(1024)
sort_kernel(const ull* __restrict__ cand,
            const unsigned* __restrict__ cnt,
            const float* __restrict__ cs,
            float* __restrict__ rows,      // [NBC][KTOP][5] score,cx,cy,w,h
            float* __restrict__ bx1, float* __restrict__ by1,
            float* __restrict__ bx2, float* __restrict__ by2,
            float* __restrict__ bar,       // SoA [NBC][ROWS]
            int* __restrict__ nselArr,
            int P, int Cfg) {
#pragma clang fp contract(off)
    int bc  = blockIdx.x;
    int b   = bc / Cfg;
    int tid = threadIdx.x;
    __shared__ ull sbuf[CAP];

    int M = (int)cnt[bc]; if (M > CAP) M = CAP;
    int nsel = M < KTOP ? M : KTOP;
    if (tid == 0) nselArr[bc] = nsel;

    int n = 1024;
    while (n < M) n <<= 1;
    for (int i = tid; i < n; i += 1024)
        sbuf[i] = (i < M) ? cand[(size_t)bc * CAP + i] : 0ull;
    __syncthreads();

    for (unsigned k = 2; k <= (unsigned)n; k <<= 1) {
        for (unsigned j = k >> 1; j > 0; j >>= 1) {
            for (unsigned i = tid; i < (unsigned)n; i += 1024) {
                unsigned ixj = i ^ j;
                if (ixj > i) {
                    bool up = ((i & k) == 0u);
                    ull a = sbuf[i], bb = sbuf[ixj];
                    if ((a > bb) == up) { sbuf[i] = bb; sbuf[ixj] = a; }
                }
            }
            __syncthreads();
        }
    }

    for (int r = tid; r < nsel; r += 1024) {
        ull e = sbuf[n - 1 - r];
        float sc = __uint_as_float((unsigned)(e >> 32));
        int idx = (int)(~(unsigned)e);
        const float* c4 = cs + ((size_t)b * P + idx) * 4;
        float cx = c4[0], cy = c4[1], w = c4[2], h = c4[3];
        float x1 = cx - w / 2.f, y1 = cy - h / 2.f;
        float x2 = cx + w / 2.f, y2 = cy + h / 2.f;
        size_t sb = (size_t)bc * ROWS + r;
        bx1[sb] = x1; by1[sb] = y1; bx2[sb] = x2; by2[sb] = y2;
        bar[sb] = fmaxf(x2 - x1, 0.f) * fmaxf(y2 - y1, 0.f);
        float* rr = rows + ((size_t)bc * KTOP + r) * 5;
        rr[0] = sc; rr[1] = cx; rr[2] = cy; rr[3] = w; rr[4] = h;
    }
}

// ---------------- Kernel 5: GPU-wide suppression bitmask matrix ----------------
__global__ void __launch_bounds__(1024)
mask_kernel(const float* __restrict__ bx1, const float* __restrict__ by1,
            const float* __restrict__ bx2, const float* __restrict__ by2,
            const float* __restrict__ bar,
            const int* __restrict__ nselArr,
            const float* __restrict__ nthp,
            ull* __restrict__ mask) {       // [NBC][ROWS][WORDS]
#pragma clang fp contract(off)
    int bc   = blockIdx.x;
    int tile = blockIdx.y;                  // 16 tiles x 64 rows
    int tid  = threadIdx.x;
    int nsel = nselArr[bc];
    float nth = *nthp;

    __shared__ float sx1[ROWS], sy1[ROWS], sx2[ROWS], sy2[ROWS], sar[ROWS];
    size_t sb = (size_t)bc * ROWS;
    if (tid < nsel) {
        sx1[tid] = bx1[sb + tid]; sy1[tid] = by1[sb + tid];
        sx2[tid] = bx2[sb + tid]; sy2[tid] = by2[sb + tid];
        sar[tid] = bar[sb + tid];
    }
    __syncthreads();

    int i = tile * 64 + (tid >> 4);
    int w = tid & 15;
    if (i >= nsel) return;

    float xi1 = sx1[i], yi1 = sy1[i], xi2 = sx2[i], yi2 = sy2[i], ai = sar[i];
    ull bits = 0ull;
    int j0 = w << 6;
    for (int jj0 = 0; jj0 < 64; ++jj0) {
        int jj = (jj0 + (w << 2)) & 63;
        int j = j0 + jj;
        if (j > i && j < nsel) {
            float ww = fmaxf(fminf(xi2, sx2[j]) - fmaxf(xi1, sx1[j]), 0.f);
            float hh = fmaxf(fminf(yi2, sy2[j]) - fmaxf(yi1, sy1[j]), 0.f);
            float inter = ww * hh;
            float uni = ai + sar[j] - inter;
            float iou = inter / fmaxf(uni, 1e-12f);
            if (iou > nth) bits |= 1ull << jj;
        }
    }
    mask[(((size_t)bc * ROWS + i) << 4) + w] = bits;
}

// ---------------- Kernel 6: chunked serial bit-OR reduction + compact + write ----------------
__global__ void __launch_bounds__(64)
reduce_pack_kernel(const ull* __restrict__ mask,
                   const int* __restrict__ nselArr,
                   const float* __restrict__ rows,
                   float* __restrict__ out) {
    int bc   = blockIdx.x;
    int lane = threadIdx.x;                 // 64 threads = 1 wave
    int nsel = nselArr[bc];
    const ull* mrow = mask + ((size_t)bc * ROWS << 4);

    __shared__ ull sm[2048];                // 2 x (64 rows x 16 words) = 16 KB

    int nchunk = (nsel + 63) >> 6;          // <= 16
    ull S = 0ull;                           // lane w<16 holds suppressed-word w

    if (nchunk > 0) {
        ull r[16];
        #pragma unroll
        for (int k = 0; k < 16; ++k) r[k] = mrow[k * 64 + lane];
        #pragma unroll
        for (int k = 0; k < 16; ++k) sm[k * 64 + lane] = r[k];

        for (int c = 0; c < nchunk; ++c) {
            int cb = (c & 1) << 10;
            int nb = ((c + 1) & 1) << 10;
            bool more = (c + 1) < nchunk;
            if (more) {
                #pragma unroll
                for (int k = 0; k < 16; ++k)
                    r[k] = mrow[(size_t)(c + 1) * 1024 + k * 64 + lane];
            }

            int rmax = nsel - (c << 6); if (rmax > 64) rmax = 64;
            ull cur   = __shfl(S, c);
            ull kbits = 0ull;
            #pragma unroll 8
            for (int i = 0; i < rmax; ++i) {
                ull di  = sm[cb + (i << 4) + c];
                ull sup = (cur >> i) & 1ull;
                cur   |= di & (sup - 1ull);
                kbits |= (sup ^ 1ull) << i;
            }

            ull kb = kbits;
            while (kb) {
                int i = __ffsll(kb) - 1;
                kb &= kb - 1ull;
                if (lane > c && lane < WORDS)
                    S |= sm[cb + (i << 4) + lane];
            }
            if (lane == c) S = cur;

            if (more) {
                #pragma unroll
                for (int k = 0; k < 16; ++k) sm[nb + k * 64 + lane] = r[k];
            }
        }
    }

    int base_i = lane << 6;
    ull valid = 0ull;
    if (lane < WORDS) {
        int rem = nsel - base_i;
        if (rem > 0) valid = (rem >= 64) ? ~0ull : ((1ull << rem) - 1ull);
    }
    ull K = (~S) & valid;
    int cpc = __popcll(K);
    int x = cpc;
    for (int d = 1; d < 64; d <<= 1) {
        int y = __shfl_up(x, d);
        if (lane >= d) x += y;
    }
    int pos = x - cpc;

    const float* rbase = rows + (size_t)bc * KTOP * 5;
    float* obase = out + (size_t)bc * KTOP * 5;
    for (int bit = 0; bit < 64; ++bit) {
        if ((K >> bit) & 1ull) {
            int i = base_i + bit;
            const float* rr = rbase + i * 5;
            float* oo = obase + pos * 5;
            oo[0] = rr[0]; oo[1] = rr[1]; oo[2] = rr[2]; oo[3] = rr[3]; oo[4] = rr[4];
            ++pos;
        }
    }
}

// ------------------------------- launcher -------------------------------
extern "C" void kernel_launch(void* const* d_in, const int* in_sizes, int n_in,
                              void* d_out, int out_size, void* d_ws, size_t ws_size,
                              hipStream_t stream) {
    (void)n_in; (void)ws_size;
    const float* loc   = (const float*)d_in[0];
    const float* conf  = (const float*)d_in[1];
    const float* prior = (const float*)d_in[2];
    const float* cth   = (const float*)d_in[3];
    const float* nth   = (const float*)d_in[4];
    float* out = (float*)d_out;

    int P   = in_sizes[2] / 4;
    int B   = in_sizes[0] / (4 * P);
    int C   = in_sizes[1] / (B * P);
    int Cfg = C - 1;
    int NBC = B * Cfg;

    // ---- carve workspace (256B aligned sections; 8B types first) ----
    char* base = (char*)d_ws;
    size_t off = 0;
    auto carve = [&](size_t bytes) { char* p = base + off; off = (off + bytes + 255) & ~(size_t)255; return p; };

    ull*      cand   = (ull*)     carve((size_t)NBC * CAP * 8);
    ull*      mask   = (ull*)     carve((size_t)NBC * ROWS * WORDS * 8);
    float*    scores = (float*)   carve((size_t)NBC * P * 4);
    float*    cs     = (float*)   carve((size_t)B * P * 4 * 4);
    float*    rows   = (float*)   carve((size_t)NBC * KTOP * 5 * 4);
    float*    bx1    = (float*)   carve((size_t)NBC * ROWS * 4);
    float*    by1    = (float*)   carve((size_t)NBC * ROWS * 4);
    float*    bx2    = (float*)   carve((size_t)NBC * ROWS * 4);
    float*    by2    = (float*)   carve((size_t)NBC * ROWS * 4);
    float*    bar    = (float*)   carve((size_t)NBC * ROWS * 4);
    unsigned* hist   = (unsigned*)carve((size_t)NBC * HB * 4 + (size_t)NBC * 4);  // hist + cnt contiguous
    unsigned* cnt    = hist + (size_t)NBC * HB;
    unsigned* pivot  = (unsigned*)carve((size_t)NBC * 4);
    int*      nselA  = (int*)     carve((size_t)NBC * 4);

    hipMemsetAsync(hist, 0, (size_t)NBC * HB * 4 + (size_t)NBC * 4, stream);
    hipMemsetAsync(out, 0, (size_t)out_size * 4, stream);

    int n1 = B * P;
    decode_kernel<<<(n1 + 255) / 256, 256, 0, stream>>>(loc, conf, prior, scores, cs, B, C, P);
    hist_kernel<<<dim3(NBC, HCHUNK), 256, 0, stream>>>(scores, cth, hist, P);
    pivot_kernel<<<NBC, 256, 0, stream>>>(hist, pivot);
    gather_kernel<<<dim3(NBC, 32), 256, 0, stream>>>(scores, pivot, cnt, cand, cth, P);
    sort_kernel<<<NBC, 1024, 0, stream>>>(cand, cnt, cs, rows, bx1, by1, bx2, by2, bar, nselA, P, Cfg);
    mask_kernel<<<dim3(NBC, ROWS / 64), 1024, 0, stream>>>(bx1, by1, bx2, by2, bar, nselA, nth, mask);
    reduce_pack_kernel<<<NBC, 64, 0, stream>>>(mask, nselA, rows, out);
}

// Round 7
// 244.429 us; speedup vs baseline: 3.3294x; 1.1991x over previous
//
#include <hip/hip_runtime.h>
#include <cstdint>
#include <cstddef>

typedef unsigned long long ull;

#define KTOP   1000
#define CAP    4096      // candidate gather capacity per (b,c)
#define HBITS  14
#define HB     (1 << HBITS)          // 16384 histogram bins (top-14 float bits)
#define HSHIFT (32 - HBITS)
#define ROWS   1024      // padded rank capacity (>= KTOP)
#define WORDS  16        // 1024 / 64 bitmask words per row
#define HCHUNK 16        // score chunks per (b,c) for the LDS histogram kernel

// ---------------- Kernel 1: softmax + SSD decode (pure streaming) ----------------
__global__ void decode_kernel(const float* __restrict__ loc,
                              const float* __restrict__ conf,
                              const float* __restrict__ prior,
                              float* __restrict__ scores,   // [B*Cfg][P]
                              float* __restrict__ cs,       // [B][P][4] center-size
                              int B, int C, int P) {
#pragma clang fp contract(off)
    int t = blockIdx.x * blockDim.x + threadIdx.x;
    if (t >= B * P) return;
    int b = t / P;
    int p = t - b * P;

    // softmax over class dim (C small)
    float x[8];
    float m = -INFINITY;
    for (int c = 0; c < C; ++c) {
        x[c] = conf[((size_t)b * C + c) * P + p];
        m = fmaxf(m, x[c]);
    }
    float sum = 0.f;
    for (int c = 0; c < C; ++c) {
        x[c] = expf(x[c] - m);
        sum += x[c];
    }
    for (int c = 1; c < C; ++c) {
        float v = x[c] / sum;
        int bc = b * (C - 1) + (c - 1);
        scores[(size_t)bc * P + p] = v;
    }

    // decode
    float l0 = loc[((size_t)b * 4 + 0) * P + p];
    float l1 = loc[((size_t)b * 4 + 1) * P + p];
    float l2 = loc[((size_t)b * 4 + 2) * P + p];
    float l3 = loc[((size_t)b * 4 + 3) * P + p];
    float pcx = prior[(size_t)p * 4 + 0];
    float pcy = prior[(size_t)p * 4 + 1];
    float pw  = prior[(size_t)p * 4 + 2];
    float ph  = prior[(size_t)p * 4 + 3];

    float cx = pcx + (l0 * 0.1f) * pw;
    float cy = pcy + (l1 * 0.1f) * ph;
    float w  = pw * expf(l2 * 0.2f);
    float h  = ph * expf(l3 * 0.2f);

    size_t o = ((size_t)b * P + p) * 4;
    cs[o + 0] = cx;
    cs[o + 1] = cy;
    cs[o + 2] = w;
    cs[o + 3] = h;
}

// ---------------- Kernel 1b: LDS-privatized score histogram ----------------
__global__ void __launch_bounds__(256)
hist_kernel(const float* __restrict__ scores,
            const float* __restrict__ cthp,
            unsigned* __restrict__ hist,     // [NBC][HB]
            int P) {
    __shared__ unsigned sh[HB / 2];          // 32 KB (16-bit packed counters)
    int bc  = blockIdx.x;
    int tid = threadIdx.x;
    float cth = *cthp;

    for (int i = tid; i < HB / 2; i += 256) sh[i] = 0u;
    __syncthreads();

    int chunk = (P + HCHUNK - 1) / HCHUNK;
    int lo = blockIdx.y * chunk;
    int hi = lo + chunk; if (hi > P) hi = P;
    const float* s = scores + (size_t)bc * P;
    for (int p = lo + tid; p < hi; p += 256) {
        float v = s[p];
        if (v >= cth) {
            unsigned bin = __float_as_uint(v) >> HSHIFT;
            atomicAdd(&sh[bin >> 1], (bin & 1u) ? 65536u : 1u);
        }
    }
    __syncthreads();

    unsigned* h = hist + (size_t)bc * HB;
    for (int i = tid; i < HB / 2; i += 256) {
        unsigned v = sh[i];
        if (v & 0xFFFFu)  atomicAdd(&h[2 * i],     v & 0xFFFFu);
        if (v >> 16)      atomicAdd(&h[2 * i + 1], v >> 16);
    }
}

// ---------------- Kernel 2: per-(b,c) pivot bin via parallel suffix scan ----------------
__global__ void __launch_bounds__(256)
pivot_kernel(const unsigned* __restrict__ hist, unsigned* __restrict__ pivot) {
    int bc  = blockIdx.x;
    int t   = threadIdx.x;
    const unsigned* h = hist + (size_t)bc * HB;
    __shared__ unsigned T[256];

    const int per = HB / 256;                // 64 bins per thread
    int base = t * per;
    unsigned S = 0;
    for (int i = 0; i < per; ++i) S += h[base + i];
    T[t] = S;
    __syncthreads();

    for (int d = 1; d < 256; d <<= 1) {
        unsigned add = (t + d < 256) ? T[t + d] : 0u;
        __syncthreads();
        T[t] += add;
        __syncthreads();
    }

    unsigned Tt = T[t];
    unsigned Tn = (t + 1 < 256) ? T[t + 1] : 0u;
    if (Tt >= (unsigned)KTOP && Tn < (unsigned)KTOP) {
        unsigned cum = Tn;
        for (int i = per - 1; i >= 0; --i) {
            cum += h[base + i];
            if (cum >= (unsigned)KTOP) { pivot[bc] = (unsigned)(base + i); break; }
        }
    }
    if (t == 0 && T[0] < (unsigned)KTOP) pivot[bc] = 0u;   // fewer than KTOP valid: take all
}

// ---------------- Kernel 3: gather with BLOCK-aggregated allocation ----------------
__global__ void __launch_bounds__(256)
gather_kernel(const float* __restrict__ scores,
              const unsigned* __restrict__ pivot,
              unsigned* __restrict__ cnt,
              ull* __restrict__ cand,
              const float* __restrict__ cthp, int P) {
    __shared__ unsigned wsum[4];
    __shared__ unsigned s_base;
    int bc = blockIdx.x;
    const float* s = scores + (size_t)bc * P;
    float cth = *cthp;
    unsigned pv = pivot[bc];
    int nchunk = gridDim.y;
    int chunk = (P + nchunk - 1) / nchunk;
    int lo = blockIdx.y * chunk;
    int hi = lo + chunk; if (hi > P) hi = P;
    int tid  = threadIdx.x;
    int lane = tid & 63;
    int wid  = tid >> 6;

    // phase 1: count
    unsigned mycnt = 0;
    for (int p = lo + tid; p < hi; p += 256) {
        float v = s[p];
        unsigned k = __float_as_uint(v);
        if (v >= cth && (k >> HSHIFT) >= pv) ++mycnt;
    }
    unsigned x = mycnt;
    for (int d = 1; d < 64; d <<= 1) {
        unsigned y = (unsigned)__shfl_up((int)x, d);
        if (lane >= d) x += y;
    }
    if (lane == 63) wsum[wid] = x;
    __syncthreads();
    if (tid == 0) {
        unsigned tot = 0;
        for (int w = 0; w < 4; ++w) { unsigned t2 = wsum[w]; wsum[w] = tot; tot += t2; }
        s_base = tot ? atomicAdd(&cnt[bc], tot) : 0u;
    }
    __syncthreads();
    unsigned off = s_base + wsum[wid] + (x - mycnt);

    // phase 2: write (chunk is L2-hot from phase 1)
    ull* cb = cand + (size_t)bc * CAP;
    for (int p = lo + tid; p < hi; p += 256) {
        float v = s[p];
        unsigned k = __float_as_uint(v);
        if (v >= cth && (k >> HSHIFT) >= pv) {
            if (off < CAP)
                cb[off] = ((ull)k << 32) | (unsigned)(~(unsigned)p);
            ++off;
        }
    }
}

// ---------------- Kernel 4: per-(b,c) bitonic sort + export sorted boxes ----------------
__global__ void __launch_bounds__(1024)
sort_kernel(const ull* __restrict__ cand,
            const unsigned* __restrict__ cnt,
            const float* __restrict__ cs,
            float* __restrict__ rows,      // [NBC][KTOP][5] score,cx,cy,w,h
            float* __restrict__ bx1, float* __restrict__ by1,
            float* __restrict__ bx2, float* __restrict__ by2,
            float* __restrict__ bar,       // SoA [NBC][ROWS]
            int* __restrict__ nselArr,
            int P, int Cfg) {
#pragma clang fp contract(off)
    int bc  = blockIdx.x;
    int b   = bc / Cfg;
    int tid = threadIdx.x;
    __shared__ ull sbuf[CAP];

    int M = (int)cnt[bc]; if (M > CAP) M = CAP;
    int nsel = M < KTOP ? M : KTOP;
    if (tid == 0) nselArr[bc] = nsel;

    int n = 1024;
    while (n < M) n <<= 1;
    for (int i = tid; i < n; i += 1024)
        sbuf[i] = (i < M) ? cand[(size_t)bc * CAP + i] : 0ull;
    __syncthreads();

    for (unsigned k = 2; k <= (unsigned)n; k <<= 1) {
        for (unsigned j = k >> 1; j > 0; j >>= 1) {
            for (unsigned i = tid; i < (unsigned)n; i += 1024) {
                unsigned ixj = i ^ j;
                if (ixj > i) {
                    bool up = ((i & k) == 0u);
                    ull a = sbuf[i], bb = sbuf[ixj];
                    if ((a > bb) == up) { sbuf[i] = bb; sbuf[ixj] = a; }
                }
            }
            __syncthreads();
        }
    }

    for (int r = tid; r < nsel; r += 1024) {
        ull e = sbuf[n - 1 - r];
        float sc = __uint_as_float((unsigned)(e >> 32));
        int idx = (int)(~(unsigned)e);
        const float* c4 = cs + ((size_t)b * P + idx) * 4;
        float cx = c4[0], cy = c4[1], w = c4[2], h = c4[3];
        float x1 = cx - w / 2.f, y1 = cy - h / 2.f;
        float x2 = cx + w / 2.f, y2 = cy + h / 2.f;
        size_t sb = (size_t)bc * ROWS + r;
        bx1[sb] = x1; by1[sb] = y1; bx2[sb] = x2; by2[sb] = y2;
        bar[sb] = fmaxf(x2 - x1, 0.f) * fmaxf(y2 - y1, 0.f);
        float* rr = rows + ((size_t)bc * KTOP + r) * 5;
        rr[0] = sc; rr[1] = cx; rr[2] = cy; rr[3] = w; rr[4] = h;
    }
}

// ---------------- Kernel 5: GPU-wide suppression bitmask matrix ----------------
__global__ void __launch_bounds__(1024)
mask_kernel(const float* __restrict__ bx1, const float* __restrict__ by1,
            const float* __restrict__ bx2, const float* __restrict__ by2,
            const float* __restrict__ bar,
            const int* __restrict__ nselArr,
            const float* __restrict__ nthp,
            ull* __restrict__ mask) {       // [NBC][ROWS][WORDS]
#pragma clang fp contract(off)
    int bc   = blockIdx.x;
    int tile = blockIdx.y;                  // 16 tiles x 64 rows
    int tid  = threadIdx.x;
    int nsel = nselArr[bc];
    float nth = *nthp;

    __shared__ float sx1[ROWS], sy1[ROWS], sx2[ROWS], sy2[ROWS], sar[ROWS];
    size_t sb = (size_t)bc * ROWS;
    if (tid < nsel) {
        sx1[tid] = bx1[sb + tid]; sy1[tid] = by1[sb + tid];
        sx2[tid] = bx2[sb + tid]; sy2[tid] = by2[sb + tid];
        sar[tid] = bar[sb + tid];
    }
    __syncthreads();

    int i = tile * 64 + (tid >> 4);
    int w = tid & 15;
    if (i >= nsel) return;

    float xi1 = sx1[i], yi1 = sy1[i], xi2 = sx2[i], yi2 = sy2[i], ai = sar[i];
    ull bits = 0ull;
    int j0 = w << 6;
    for (int jj0 = 0; jj0 < 64; ++jj0) {
        int jj = (jj0 + (w << 2)) & 63;
        int j = j0 + jj;
        if (j > i && j < nsel) {
            float ww = fmaxf(fminf(xi2, sx2[j]) - fmaxf(xi1, sx1[j]), 0.f);
            float hh = fmaxf(fminf(yi2, sy2[j]) - fmaxf(yi1, sy1[j]), 0.f);
            float inter = ww * hh;
            float uni = ai + sar[j] - inter;
            float iou = inter / fmaxf(uni, 1e-12f);
            if (iou > nth) bits |= 1ull << jj;
        }
    }
    mask[(((size_t)bc * ROWS + i) << 4) + w] = bits;
}

// ---------------- Kernel 6: chunked serial bit-OR reduction + compact + write ----------------
// One wave per (b,c). Serial recurrence runs on word c only (all lanes
// redundantly); the cross-word suppression is applied per chunk by ALL 64
// lanes: lane = g*16+w reads its 16-row group's word w with UNCONDITIONAL
// pipelined LDS reads (mask via sign-extend of the kept bit — no divergent
// while loop, no per-iteration waitcnt), then 2 shfl_xor ORs combine groups.
// Words < c of any row are structurally zero (mask holds only j>i bits) and
// word c is idempotent vs `cur`, so unconditional application is safe.
__global__ void __launch_bounds__(64)
reduce_pack_kernel(const ull* __restrict__ mask,
                   const int* __restrict__ nselArr,
                   const float* __restrict__ rows,
                   float* __restrict__ out) {
    int bc   = blockIdx.x;
    int lane = threadIdx.x;                 // 64 threads = 1 wave
    int nsel = nselArr[bc];
    const ull* mrow = mask + ((size_t)bc * ROWS << 4);

    __shared__ ull sm[2048];                // 2 x (64 rows x 16 words) = 16 KB

    int nchunk = (nsel + 63) >> 6;          // <= 16
    ull S = 0ull;                           // lane w<16 holds suppressed-word w
    int g = lane >> 4;                      // row-group 0..3 for bulk apply
    int w = lane & 15;                      // word index for bulk apply

    if (nchunk > 0) {
        ull r[16];
        #pragma unroll
        for (int k = 0; k < 16; ++k) r[k] = mrow[k * 64 + lane];
        #pragma unroll
        for (int k = 0; k < 16; ++k) sm[k * 64 + lane] = r[k];

        for (int c = 0; c < nchunk; ++c) {
            int cb = (c & 1) << 10;
            int nb = ((c + 1) & 1) << 10;
            bool more = (c + 1) < nchunk;
            if (more) {
                #pragma unroll
                for (int k = 0; k < 16; ++k)
                    r[k] = mrow[(size_t)(c + 1) * 1024 + k * 64 + lane];
            }

            // ---- serial within-chunk greedy on word c (all lanes redundant) ----
            int rmax = nsel - (c << 6); if (rmax > 64) rmax = 64;
            ull cur   = __shfl(S, c);
            ull kbits = 0ull;
            #pragma unroll 8
            for (int i = 0; i < rmax; ++i) {
                ull di  = sm[cb + (i << 4) + c];     // broadcast read (off-chain)
                ull sup = (cur >> i) & 1ull;
                cur   |= di & (sup - 1ull);
                kbits |= (sup ^ 1ull) << i;
            }

            // ---- bulk apply: lane (g,w) ORs kept rows of group g, word w ----
            unsigned sub = (unsigned)((kbits >> (g << 4)) & 0xFFFFull);
            int rbase2 = cb + (g << 8) + w;          // (g*16 rows) << 4 words
            ull part = 0ull;
            #pragma unroll
            for (int i = 0; i < 16; ++i) {
                ull v = sm[rbase2 + (i << 4)];       // unconditional, pipelined
                part |= v & (ull)(0ll - (long long)((sub >> i) & 1u));
            }
            part |= __shfl_xor(part, 16);
            part |= __shfl_xor(part, 32);
            S |= part;                               // lanes 0..15 meaningful
            if (lane == c) S = cur;                  // finalize word c

            if (more) {
                #pragma unroll
                for (int k = 0; k < 16; ++k) sm[nb + k * 64 + lane] = r[k];
            }
        }
    }

    // ---- kept bitmap -> compact positions -> write packed rows ----
    int base_i = lane << 6;
    ull valid = 0ull;
    if (lane < WORDS) {
        int rem = nsel - base_i;
        if (rem > 0) valid = (rem >= 64) ? ~0ull : ((1ull << rem) - 1ull);
    }
    ull K = (~S) & valid;
    int cpc = __popcll(K);
    int x = cpc;
    for (int d = 1; d < 64; d <<= 1) {
        int y = __shfl_up(x, d);
        if (lane >= d) x += y;
    }
    int pos = x - cpc;

    const float* rbase = rows + (size_t)bc * KTOP * 5;
    float* obase = out + (size_t)bc * KTOP * 5;
    for (int bit = 0; bit < 64; ++bit) {
        if ((K >> bit) & 1ull) {
            int i = base_i + bit;
            const float* rr = rbase + i * 5;
            float* oo = obase + pos * 5;
            oo[0] = rr[0]; oo[1] = rr[1]; oo[2] = rr[2]; oo[3] = rr[3]; oo[4] = rr[4];
            ++pos;
        }
    }
}

// ------------------------------- launcher -------------------------------
extern "C" void kernel_launch(void* const* d_in, const int* in_sizes, int n_in,
                              void* d_out, int out_size, void* d_ws, size_t ws_size,
                              hipStream_t stream) {
    (void)n_in; (void)ws_size;
    const float* loc   = (const float*)d_in[0];
    const float* conf  = (const float*)d_in[1];
    const float* prior = (const float*)d_in[2];
    const float* cth   = (const float*)d_in[3];
    const float* nth   = (const float*)d_in[4];
    float* out = (float*)d_out;

    int P   = in_sizes[2] / 4;
    int B   = in_sizes[0] / (4 * P);
    int C   = in_sizes[1] / (B * P);
    int Cfg = C - 1;
    int NBC = B * Cfg;

    // ---- carve workspace (256B aligned sections; 8B types first) ----
    char* base = (char*)d_ws;
    size_t off = 0;
    auto carve = [&](size_t bytes) { char* p = base + off; off = (off + bytes + 255) & ~(size_t)255; return p; };

    ull*      cand   = (ull*)     carve((size_t)NBC * CAP * 8);
    ull*      mask   = (ull*)     carve((size_t)NBC * ROWS * WORDS * 8);
    float*    scores = (float*)   carve((size_t)NBC * P * 4);
    float*    cs     = (float*)   carve((size_t)B * P * 4 * 4);
    float*    rows   = (float*)   carve((size_t)NBC * KTOP * 5 * 4);
    float*    bx1    = (float*)   carve((size_t)NBC * ROWS * 4);
    float*    by1    = (float*)   carve((size_t)NBC * ROWS * 4);
    float*    bx2    = (float*)   carve((size_t)NBC * ROWS * 4);
    float*    by2    = (float*)   carve((size_t)NBC * ROWS * 4);
    float*    bar    = (float*)   carve((size_t)NBC * ROWS * 4);
    unsigned* hist   = (unsigned*)carve((size_t)NBC * HB * 4 + (size_t)NBC * 4);  // hist + cnt contiguous
    unsigned* cnt    = hist + (size_t)NBC * HB;
    unsigned* pivot  = (unsigned*)carve((size_t)NBC * 4);
    int*      nselA  = (int*)     carve((size_t)NBC * 4);

    hipMemsetAsync(hist, 0, (size_t)NBC * HB * 4 + (size_t)NBC * 4, stream);
    hipMemsetAsync(out, 0, (size_t)out_size * 4, stream);

    int n1 = B * P;
    decode_kernel<<<(n1 + 255) / 256, 256, 0, stream>>>(loc, conf, prior, scores, cs, B, C, P);
    hist_kernel<<<dim3(NBC, HCHUNK), 256, 0, stream>>>(scores, cth, hist, P);
    pivot_kernel<<<NBC, 256, 0, stream>>>(hist, pivot);
    gather_kernel<<<dim3(NBC, 32), 256, 0, stream>>>(scores, pivot, cnt, cand, cth, P);
    sort_kernel<<<NBC, 1024, 0, stream>>>(cand, cnt, cs, rows, bx1, by1, bx2, by2, bar, nselA, P, Cfg);
    mask_kernel<<<dim3(NBC, ROWS / 64), 1024, 0, stream>>>(bx1, by1, bx2, by2, bar, nselA, nth, mask);
    reduce_pack_kernel<<<NBC, 64, 0, stream>>>(mask, nselA, rows, out);
}